// Round 2
// baseline (3285.250 us; speedup 1.0000x reference)
//
#include <hip/hip_runtime.h>

#define N_NODE  40000
#define DIM     128
#define N_REL   8
#define N_EDGES 640000
#define PER_REL (N_EDGES / N_REL)
#define BS      128
#define SQ      50

typedef unsigned int u32;

// ------------------------------------------------------------------
// ego[h[e]] += v[e] * emb[t[e]]   — 32 threads/edge, 4 dims each
__global__ void spmm_kernel(const float* __restrict__ x, const float* __restrict__ vv,
                            const int* __restrict__ hl, const int* __restrict__ tl,
                            float* __restrict__ out) {
  int gid = blockIdx.x * 256 + threadIdx.x;
  int e = gid >> 5;
  int q = (gid & 31) << 2;
  float val = vv[e];
  int tn = tl[e], hn = hl[e];
  float4 xv = *reinterpret_cast<const float4*>(x + (size_t)tn * DIM + q);
  float* o = out + (size_t)hn * DIM + q;
  atomicAdd(o + 0, val * xv.x);
  atomicAdd(o + 1, val * xv.y);
  atomicAdd(o + 2, val * xv.z);
  atomicAdd(o + 3, val * xv.w);
}

// ego2[h[e]] += (v[e]/rowsum[h[e]]) * ego1[t[e]]   (softmax-normalize fused)
__global__ void spmm_norm_kernel(const float* __restrict__ x, const float* __restrict__ vv,
                                 const float* __restrict__ rsum,
                                 const int* __restrict__ hl, const int* __restrict__ tl,
                                 float* __restrict__ out) {
  int gid = blockIdx.x * 256 + threadIdx.x;
  int e = gid >> 5;
  int q = (gid & 31) << 2;
  int tn = tl[e], hn = hl[e];
  float val = vv[e] / rsum[hn];
  float4 xv = *reinterpret_cast<const float4*>(x + (size_t)tn * DIM + q);
  float* o = out + (size_t)hn * DIM + q;
  atomicAdd(o + 0, val * xv.x);
  atomicAdd(o + 1, val * xv.y);
  atomicAdd(o + 2, val * xv.z);
  atomicAdd(o + 3, val * xv.w);
}

// ------------------------------------------------------------------
// proj[n][j] = sum_k ego[n][k] * W_r[k][j]
// 256 threads: group (tid>>7) owns an 8-node register tile, col = tid&127.
#define PROJ_NODES 160
__global__ void __launch_bounds__(256)
proj_kernel(const float* __restrict__ ego, const float* __restrict__ transM,
            float* __restrict__ proj, int r) {
  __shared__ float Wl[DIM * DIM];     // 64 KB
  __shared__ float rows[16 * DIM];    // 8 KB
  int tid = threadIdx.x;
  int grp = tid >> 7;
  int col = tid & 127;
  const float* W = transM + (size_t)r * DIM * DIM;
  for (int x = tid; x < DIM * DIM; x += 256) Wl[x] = W[x];
  int base = blockIdx.x * PROJ_NODES;
  for (int g = 0; g < PROJ_NODES; g += 16) {
    __syncthreads();                  // W ready (g==0) / rows free (g>0)
    const float* src = ego + (size_t)(base + g + grp * 8) * DIM;
    #pragma unroll
    for (int u = 0; u < 8; u++) rows[(grp * 8 + u) * DIM + col] = src[u * DIM + col];
    __syncthreads();
    float acc[8] = {0.f,0.f,0.f,0.f,0.f,0.f,0.f,0.f};
    #pragma unroll 4
    for (int k = 0; k < DIM; k += 4) {
      float w0 = Wl[(k + 0) * DIM + col];
      float w1 = Wl[(k + 1) * DIM + col];
      float w2 = Wl[(k + 2) * DIM + col];
      float w3 = Wl[(k + 3) * DIM + col];
      #pragma unroll
      for (int u = 0; u < 8; u++) {
        float4 rv = *reinterpret_cast<const float4*>(&rows[(grp * 8 + u) * DIM + k]);
        acc[u] += rv.x * w0 + rv.y * w1 + rv.z * w2 + rv.w * w3;
      }
    }
    float* dst = proj + (size_t)(base + g + grp * 8) * DIM;
    #pragma unroll
    for (int u = 0; u < 8; u++) dst[u * DIM + col] = acc[u];
  }
}

// ------------------------------------------------------------------
// vnew[e] = sum_d [ tanh(proj[t]) * proj[h] + r_emb[r] ]_d      one wave/edge
__global__ void edge_attn(const float* __restrict__ proj, const int* __restrict__ hl,
                          const int* __restrict__ tl, const float* __restrict__ remb,
                          float* __restrict__ vnew, int ebase) {
  int lane = threadIdx.x & 63;
  int e = ebase + blockIdx.x * 4 + (threadIdx.x >> 6);
  int hn = hl[e], tn = tl[e];
  const float* ph = proj + (size_t)hn * DIM;
  const float* pt = proj + (size_t)tn * DIM;
  float s = 0.f;
  #pragma unroll
  for (int half = 0; half < 2; half++) {
    int d = lane + half * 64;
    s += tanhf(pt[d]) * ph[d] + remb[d];
  }
  #pragma unroll
  for (int off = 32; off; off >>= 1) s += __shfl_xor(s, off, 64);
  if (lane == 0) vnew[e] = s;
}

// ------------------------------------------------------------------
// segment max via order-preserving uint map (init key 0 == below all finite)
__global__ void row_max(const float* __restrict__ vnew, const int* __restrict__ hl,
                        u32* __restrict__ rmax) {
  int e = blockIdx.x * 256 + threadIdx.x;
  if (e >= N_EDGES) return;
  union { float f; u32 i; } c; c.f = vnew[e];
  u32 k = (c.i >> 31) ? ~c.i : (c.i | 0x80000000u);
  atomicMax(rmax + hl[e], k);
}

__global__ void row_exp(const float* __restrict__ vnew, const int* __restrict__ hl,
                        const u32* __restrict__ rmax,
                        float* __restrict__ v, float* __restrict__ rsum) {
  int e = blockIdx.x * 256 + threadIdx.x;
  if (e >= N_EDGES) return;
  int hn = hl[e];
  u32 k = rmax[hn];
  union { u32 i; float f; } c; c.i = (k >> 31) ? (k ^ 0x80000000u) : ~k;
  float ex = expf(vnew[e] - c.f);
  v[e] = ex;
  atomicAdd(rsum + hn, ex);
}

// ------------------------------------------------------------------
// hidden[b,i,:] = local_agg(node)[b,i,:] + local_agg(kg)[b,i,:]
// One block per b; wave per i (strided); online softmax; lane owns dims d, d+64.
__global__ void __launch_bounds__(256)
local_agg_kernel(const float* __restrict__ emb, const float* __restrict__ ego1,
                 const float* __restrict__ ego2, const int* __restrict__ inp,
                 const int* __restrict__ Aadj,
                 const float* __restrict__ a0, const float* __restrict__ a1,
                 const float* __restrict__ a2, const float* __restrict__ a3,
                 float* __restrict__ out_hidden, float* __restrict__ out_node) {
  __shared__ float hN[SQ][DIM];   // node embeds
  __shared__ float hK[SQ][DIM];   // kg embeds
  __shared__ float aS[4][DIM];
  int b = blockIdx.x;
  int tid = threadIdx.x;
  for (int x = tid; x < 4 * DIM; x += 256) {
    int kk = x >> 7, d = x & 127;
    const float* ap = (kk == 0) ? a0 : (kk == 1) ? a1 : (kk == 2) ? a2 : a3;
    aS[kk][d] = ap[d];
  }
  for (int x = tid; x < SQ * DIM; x += 256) {
    int s = x >> 7, d = x & 127;
    int node = inp[b * SQ + s];
    float uv = emb[(size_t)node * DIM + d];
    hN[s][d] = uv;
    out_node[(size_t)(b * SQ + s) * DIM + d] = uv;   // output 1 passthrough
    hK[s][d] = 0.5f * (ego1[(size_t)node * DIM + d] + ego2[(size_t)node * DIM + d]);
  }
  __syncthreads();
  int wv = tid >> 6, lane = tid & 63;
  for (int i = wv; i < SQ; i += 4) {
    int d0 = lane, d1 = lane + 64;
    float hiN0 = hN[i][d0], hiN1 = hN[i][d1];
    float hiK0 = hK[i][d0], hiK1 = hK[i][d1];
    float mN = -__builtin_inff(), sN = 0.f, oN0 = 0.f, oN1 = 0.f;
    float mK = -__builtin_inff(), sK = 0.f, oK0 = 0.f, oK1 = 0.f;
    for (int j = 0; j < SQ; j++) {
      int ad = Aadj[(b * SQ + i) * SQ + j];   // wave-uniform
      float lN = -9e15f, lK = -9e15f;
      if (ad > 0) {                            // uniform branch
        float A0 = aS[ad - 1][d0], A1 = aS[ad - 1][d1];
        float pN0 = hiN0 * hN[j][d0]; pN0 = pN0 > 0.f ? pN0 : 0.2f * pN0;
        float pN1 = hiN1 * hN[j][d1]; pN1 = pN1 > 0.f ? pN1 : 0.2f * pN1;
        float pK0 = hiK0 * hK[j][d0]; pK0 = pK0 > 0.f ? pK0 : 0.2f * pK0;
        float pK1 = hiK1 * hK[j][d1]; pK1 = pK1 > 0.f ? pK1 : 0.2f * pK1;
        float eN = pN0 * A0 + pN1 * A1;
        float eK = pK0 * A0 + pK1 * A1;
        #pragma unroll
        for (int off = 32; off; off >>= 1) {
          eN += __shfl_xor(eN, off, 64);
          eK += __shfl_xor(eK, off, 64);
        }
        lN = eN; lK = eK;                      // all lanes hold full dot
      }
      float hj0 = hN[j][d0], hj1 = hN[j][d1];
      float g0 = hK[j][d0],  g1 = hK[j][d1];
      float mn = fmaxf(mN, lN);
      float sc = expf(mN - mn);
      float p  = expf(lN - mn);
      sN = sN * sc + p; oN0 = oN0 * sc + p * hj0; oN1 = oN1 * sc + p * hj1; mN = mn;
      float mk  = fmaxf(mK, lK);
      float sck = expf(mK - mk);
      float pk  = expf(lK - mk);
      sK = sK * sck + pk; oK0 = oK0 * sck + pk * g0; oK1 = oK1 * sck + pk * g1; mK = mk;
    }
    float r0 = oN0 / sN + oK0 / sK;
    float r1 = oN1 / sN + oK1 / sK;
    out_hidden[(size_t)(b * SQ + i) * DIM + d0] = r0;
    out_hidden[(size_t)(b * SQ + i) * DIM + d1] = r1;
  }
}

// ------------------------------------------------------------------
extern "C" void kernel_launch(void* const* d_in, const int* in_sizes, int n_in,
                              void* d_out, int out_size, void* d_ws, size_t ws_size,
                              hipStream_t stream) {
  const int*   inputs = (const int*)d_in[0];
  const int*   Aadj   = (const int*)d_in[1];
  // d_in[2] mask_item: unused by the reference forward
  const float* emb    = (const float*)d_in[3];
  const float* rembw  = (const float*)d_in[4];
  const float* transM = (const float*)d_in[5];
  const float* a0     = (const float*)d_in[6];
  const float* a1     = (const float*)d_in[7];
  const float* a2     = (const float*)d_in[8];
  const float* a3     = (const float*)d_in[9];
  const float* ain    = (const float*)d_in[10];
  const int*   hl     = (const int*)d_in[11];
  const int*   tl     = (const int*)d_in[12];

  // workspace layout (~66.9 MB total)
  float* ego1 = (float*)d_ws;
  float* ego2 = ego1 + (size_t)N_NODE * DIM;
  float* proj = ego2 + (size_t)N_NODE * DIM;
  float* vnew = proj + (size_t)N_NODE * DIM;
  float* vbuf = vnew + N_EDGES;
  u32*   rmax = (u32*)(vbuf + N_EDGES);
  float* rsum = (float*)(rmax + N_NODE);

  float* out_hidden = (float*)d_out;
  float* out_node   = out_hidden + (size_t)BS * SQ * DIM;

  hipMemsetAsync(ego1, 0, (size_t)N_NODE * DIM * 4, stream);
  hipMemsetAsync(ego2, 0, (size_t)N_NODE * DIM * 4, stream);
  hipMemsetAsync(rmax, 0, (size_t)N_NODE * 4, stream);
  hipMemsetAsync(rsum, 0, (size_t)N_NODE * 4, stream);

  // hop 0: ego1 = spmm(a_in, h, t, embedding)
  spmm_kernel<<<N_EDGES * 32 / 256, 256, 0, stream>>>(emb, ain, hl, tl, ego1);

  // update_attention: per relation, project all nodes then score that relation's edges
  for (int r = 0; r < N_REL; r++) {
    proj_kernel<<<N_NODE / PROJ_NODES, 256, 0, stream>>>(ego1, transM, proj, r);
    edge_attn<<<PER_REL / 4, 256, 0, stream>>>(proj, hl, tl, rembw + r * DIM, vnew,
                                               r * PER_REL);
  }

  // sparse row softmax over h rows
  row_max<<<N_EDGES / 256, 256, 0, stream>>>(vnew, hl, rmax);
  row_exp<<<N_EDGES / 256, 256, 0, stream>>>(vnew, hl, rmax, vbuf, rsum);

  // hop 1: ego2 = spmm(softmax(vnew), h, t, ego1)   (normalization fused)
  spmm_norm_kernel<<<N_EDGES * 32 / 256, 256, 0, stream>>>(ego1, vbuf, rsum, hl, tl, ego2);

  // session-local double attention + node_embeds passthrough
  local_agg_kernel<<<BS, 256, 0, stream>>>(emb, ego1, ego2, inputs, Aadj,
                                           a0, a1, a2, a3, out_hidden, out_node);
}

// Round 3
// 829.675 us; speedup vs baseline: 3.9597x; 3.9597x over previous
//
#include <hip/hip_runtime.h>

#define N_NODE  40000
#define DIM     128
#define N_REL   8
#define N_EDGES 640000
#define PER_REL (N_EDGES / N_REL)
#define BS      128
#define SQ      50
#define NB      ((N_NODE + 255) / 256)   // 157 scan blocks

typedef unsigned int u32;

// ==================================================================
// CSR build: histogram -> exclusive scan -> scatter
// ==================================================================
__global__ void hist_kernel(const int* __restrict__ hl, int* __restrict__ cnt) {
  int e = blockIdx.x * 256 + threadIdx.x;
  if (e < N_EDGES) atomicAdd(&cnt[hl[e]], 1);
}

__global__ void bsum_kernel(const int* __restrict__ cnt, int* __restrict__ bsum) {
  __shared__ int sd[256];
  int i = blockIdx.x * 256 + threadIdx.x;
  sd[threadIdx.x] = (i < N_NODE) ? cnt[i] : 0;
  __syncthreads();
  for (int o = 128; o; o >>= 1) {
    if (threadIdx.x < o) sd[threadIdx.x] += sd[threadIdx.x + o];
    __syncthreads();
  }
  if (!threadIdx.x) bsum[blockIdx.x] = sd[0];
}

__global__ void scan_bsum_kernel(int* __restrict__ bsum) {   // single block, NB<=256
  __shared__ int sd[256];
  int t = threadIdx.x;
  int orig = (t < NB) ? bsum[t] : 0;
  sd[t] = orig;
  __syncthreads();
  for (int o = 1; o < 256; o <<= 1) {
    int v = (t >= o) ? sd[t - o] : 0;
    __syncthreads();
    sd[t] += v;
    __syncthreads();
  }
  if (t < NB) bsum[t] = sd[t] - orig;   // exclusive
}

__global__ void scan_final_kernel(const int* __restrict__ cnt, const int* __restrict__ bsum,
                                  int* __restrict__ rowptr) {
  __shared__ int sd[256];
  int t = threadIdx.x;
  int i = blockIdx.x * 256 + t;
  int orig = (i < N_NODE) ? cnt[i] : 0;
  sd[t] = orig;
  __syncthreads();
  for (int o = 1; o < 256; o <<= 1) {
    int v = (t >= o) ? sd[t - o] : 0;
    __syncthreads();
    sd[t] += v;
    __syncthreads();
  }
  int ex = sd[t] - orig + bsum[blockIdx.x];
  if (i < N_NODE) {
    rowptr[i] = ex;
    if (i == N_NODE - 1) rowptr[N_NODE] = ex + orig;
  }
}

// pos slots filled back-to-front via atomicSub on cnt (leaves cnt zeroed)
__global__ void scatter_kernel(const int* __restrict__ hl, const int* __restrict__ tl,
                               const float* __restrict__ ain, const int* __restrict__ rowptr,
                               int* __restrict__ cnt, int* __restrict__ ipos,
                               int* __restrict__ tperm, float* __restrict__ vperm) {
  int e = blockIdx.x * 256 + threadIdx.x;
  if (e >= N_EDGES) return;
  int hn = hl[e];
  int c = atomicSub(&cnt[hn], 1);            // old value: count..1
  int pos = rowptr[hn + 1] - c;
  ipos[e] = pos;
  tperm[pos] = tl[e];
  vperm[pos] = ain[e];
}

// ==================================================================
// CSR spmm: out[r] = sum_{p in row r} vals[p] * x[tperm[p]]
// one wave per row; lane owns dims {2*lane, 2*lane+1}
// ==================================================================
__global__ void __launch_bounds__(256)
spmm_csr(const float* __restrict__ x, const float* __restrict__ vals,
         const int* __restrict__ tperm, const int* __restrict__ rowptr,
         float* __restrict__ out) {
  int row = (blockIdx.x * 256 + threadIdx.x) >> 6;
  if (row >= N_NODE) return;
  int lane = threadIdx.x & 63;
  int lo = rowptr[row], n = rowptr[row + 1] - lo;
  float ax = 0.f, ay = 0.f;
  const float* xb = x + 2 * lane;
  int p = 0;
  for (; p + 1 < n; p += 2) {
    int   t0 = tperm[lo + p],     t1 = tperm[lo + p + 1];
    float v0 = vals[lo + p],      v1 = vals[lo + p + 1];
    float2 x0 = *reinterpret_cast<const float2*>(xb + (size_t)t0 * DIM);
    float2 x1 = *reinterpret_cast<const float2*>(xb + (size_t)t1 * DIM);
    ax += v0 * x0.x + v1 * x1.x;
    ay += v0 * x0.y + v1 * x1.y;
  }
  if (p < n) {
    int   t0 = tperm[lo + p];
    float v0 = vals[lo + p];
    float2 x0 = *reinterpret_cast<const float2*>(xb + (size_t)t0 * DIM);
    ax += v0 * x0.x;
    ay += v0 * x0.y;
  }
  float2 r; r.x = ax; r.y = ay;
  *reinterpret_cast<float2*>(out + (size_t)row * DIM + 2 * lane) = r;
}

// ==================================================================
// proj = ego @ W_r  (f32 GEMM, register-tiled)
// block: 64 nodes x 128 cols; thread (ty=tid>>5 in 0..7, tx=tid&31):
//   nodes u*8+ty (u=0..7), cols tx*4..+3  -> acc 8x float4
// ==================================================================
__global__ void __launch_bounds__(256)
proj_gemm(const float* __restrict__ ego, const float* __restrict__ Wg,
          float* __restrict__ proj) {
  __shared__ float Ws[DIM * DIM];        // 64 KB
  __shared__ float rows[64 * 132];       // 33.8 KB (pad 132 keeps 16B align, spreads banks)
  int tid = threadIdx.x;
  int tx = tid & 31, ty = tid >> 5;
  for (int x = tid; x < DIM * DIM; x += 256) Ws[x] = Wg[x];
  int base = blockIdx.x * 64;
  for (int x = tid; x < 64 * DIM; x += 256) {
    int n = x >> 7, k = x & 127;
    rows[n * 132 + k] = ego[(size_t)(base + n) * DIM + k];
  }
  __syncthreads();
  float4 acc[8];
  #pragma unroll
  for (int u = 0; u < 8; u++) acc[u] = make_float4(0.f, 0.f, 0.f, 0.f);
  #pragma unroll 2
  for (int k = 0; k < DIM; k += 4) {
    float4 w0 = *reinterpret_cast<const float4*>(Ws + (k + 0) * DIM + (tx << 2));
    float4 w1 = *reinterpret_cast<const float4*>(Ws + (k + 1) * DIM + (tx << 2));
    float4 w2 = *reinterpret_cast<const float4*>(Ws + (k + 2) * DIM + (tx << 2));
    float4 w3 = *reinterpret_cast<const float4*>(Ws + (k + 3) * DIM + (tx << 2));
    #pragma unroll
    for (int u = 0; u < 8; u++) {
      float4 rv = *reinterpret_cast<const float4*>(rows + (u * 8 + ty) * 132 + k);
      acc[u].x += rv.x * w0.x + rv.y * w1.x + rv.z * w2.x + rv.w * w3.x;
      acc[u].y += rv.x * w0.y + rv.y * w1.y + rv.z * w2.y + rv.w * w3.y;
      acc[u].z += rv.x * w0.z + rv.y * w1.z + rv.z * w2.z + rv.w * w3.z;
      acc[u].w += rv.x * w0.w + rv.y * w1.w + rv.z * w2.w + rv.w * w3.w;
    }
  }
  #pragma unroll
  for (int u = 0; u < 8; u++) {
    *reinterpret_cast<float4*>(proj + (size_t)(base + u * 8 + ty) * DIM + (tx << 2)) = acc[u];
  }
}

// ==================================================================
// vnew[ipos[e]] = sum_d [ tanh(proj[t]) * proj[h] + r_emb ]_d    one wave/edge
// ==================================================================
__global__ void edge_attn(const float* __restrict__ proj, const int* __restrict__ hl,
                          const int* __restrict__ tl, const float* __restrict__ remb,
                          const int* __restrict__ ipos, float* __restrict__ vperm,
                          int ebase) {
  int lane = threadIdx.x & 63;
  int e = ebase + blockIdx.x * 4 + (threadIdx.x >> 6);
  int hn = hl[e], tn = tl[e];
  const float* ph = proj + (size_t)hn * DIM;
  const float* pt = proj + (size_t)tn * DIM;
  float s = 0.f;
  #pragma unroll
  for (int half = 0; half < 2; half++) {
    int d = lane + half * 64;
    s += tanhf(pt[d]) * ph[d] + remb[d];
  }
  #pragma unroll
  for (int off = 32; off; off >>= 1) s += __shfl_xor(s, off, 64);
  if (lane == 0) vperm[ipos[e]] = s;
}

// ==================================================================
// per-row softmax over CSR segment, in place (normalized weights)
// ==================================================================
__global__ void __launch_bounds__(256)
rowsoftmax(const int* __restrict__ rowptr, float* __restrict__ v) {
  int row = (blockIdx.x * 256 + threadIdx.x) >> 6;
  if (row >= N_NODE) return;
  int lane = threadIdx.x & 63;
  int lo = rowptr[row], n = rowptr[row + 1] - lo;
  if (n == 0) return;
  float m = -3.4e38f;
  for (int p = lane; p < n; p += 64) m = fmaxf(m, v[lo + p]);
  #pragma unroll
  for (int o = 32; o; o >>= 1) m = fmaxf(m, __shfl_xor(m, o, 64));
  float s = 0.f;
  for (int p = lane; p < n; p += 64) {
    float ex = __expf(v[lo + p] - m);
    v[lo + p] = ex;
    s += ex;
  }
  #pragma unroll
  for (int o = 32; o; o >>= 1) s += __shfl_xor(s, o, 64);
  float inv = 1.f / s;
  for (int p = lane; p < n; p += 64) v[lo + p] *= inv;
}

// ==================================================================
// local_agg: block = (b, which); which 0 -> node-embed agg (+passthrough),
// which 1 -> kg agg into tmpK. 512 threads, wave per i (strided by 8).
// ==================================================================
__global__ void __launch_bounds__(512)
local_agg2(const float* __restrict__ emb, const float* __restrict__ ego1,
           const float* __restrict__ ego2, const int* __restrict__ inp,
           const int* __restrict__ Aadj,
           const float* __restrict__ a0, const float* __restrict__ a1,
           const float* __restrict__ a2, const float* __restrict__ a3,
           float* __restrict__ out_hidden, float* __restrict__ out_node,
           float* __restrict__ tmpK) {
  __shared__ float h[SQ][DIM];    // 25.6 KB
  __shared__ float aS[4][DIM];
  int b = blockIdx.x >> 1, which = blockIdx.x & 1;
  int tid = threadIdx.x;
  if (tid < 4 * DIM) {
    int kk = tid >> 7, d = tid & 127;
    const float* ap = (kk == 0) ? a0 : (kk == 1) ? a1 : (kk == 2) ? a2 : a3;
    aS[kk][d] = ap[d];
  }
  for (int x = tid; x < SQ * DIM; x += 512) {
    int s = x >> 7, d = x & 127;
    int node = inp[b * SQ + s];
    if (which == 0) {
      float uv = emb[(size_t)node * DIM + d];
      h[s][d] = uv;
      out_node[(size_t)(b * SQ + s) * DIM + d] = uv;
    } else {
      h[s][d] = 0.5f * (ego1[(size_t)node * DIM + d] + ego2[(size_t)node * DIM + d]);
    }
  }
  __syncthreads();
  int wv = tid >> 6, lane = tid & 63;
  float* dst = (which == 0) ? out_hidden : tmpK;
  for (int i = wv; i < SQ; i += 8) {
    int d0 = lane, d1 = lane + 64;
    float hi0 = h[i][d0], hi1 = h[i][d1];
    float m = -__builtin_inff(), sden = 0.f, o0 = 0.f, o1 = 0.f;
    for (int j = 0; j < SQ; j++) {
      int ad = Aadj[(b * SQ + i) * SQ + j];   // wave-uniform
      float l = -9e15f;
      float hj0 = h[j][d0], hj1 = h[j][d1];
      if (ad > 0) {                            // uniform branch
        float A0 = aS[ad - 1][d0], A1 = aS[ad - 1][d1];
        float p0 = hi0 * hj0; p0 = p0 > 0.f ? p0 : 0.2f * p0;
        float p1 = hi1 * hj1; p1 = p1 > 0.f ? p1 : 0.2f * p1;
        float ee = p0 * A0 + p1 * A1;
        #pragma unroll
        for (int off = 32; off; off >>= 1) ee += __shfl_xor(ee, off, 64);
        l = ee;
      }
      float mn = fmaxf(m, l);
      float sc = __expf(m - mn);
      float p  = __expf(l - mn);
      sden = sden * sc + p;
      o0 = o0 * sc + p * hj0;
      o1 = o1 * sc + p * hj1;
      m = mn;
    }
    dst[(size_t)(b * SQ + i) * DIM + d0] = o0 / sden;
    dst[(size_t)(b * SQ + i) * DIM + d1] = o1 / sden;
  }
}

__global__ void add_kernel(float* __restrict__ out, const float* __restrict__ add) {
  int i = blockIdx.x * 256 + threadIdx.x;
  float4 a = reinterpret_cast<const float4*>(add)[i];
  float4 o = reinterpret_cast<float4*>(out)[i];
  o.x += a.x; o.y += a.y; o.z += a.z; o.w += a.w;
  reinterpret_cast<float4*>(out)[i] = o;
}

// ==================================================================
extern "C" void kernel_launch(void* const* d_in, const int* in_sizes, int n_in,
                              void* d_out, int out_size, void* d_ws, size_t ws_size,
                              hipStream_t stream) {
  const int*   inputs = (const int*)d_in[0];
  const int*   Aadj   = (const int*)d_in[1];
  const float* emb    = (const float*)d_in[3];
  const float* rembw  = (const float*)d_in[4];
  const float* transM = (const float*)d_in[5];
  const float* a0     = (const float*)d_in[6];
  const float* a1     = (const float*)d_in[7];
  const float* a2     = (const float*)d_in[8];
  const float* a3     = (const float*)d_in[9];
  const float* ain    = (const float*)d_in[10];
  const int*   hl     = (const int*)d_in[11];
  const int*   tl     = (const int*)d_in[12];

  // workspace layout (66.88 MB, matches prior proven footprint):
  float* ego1   = (float*)d_ws;                         // 5.12M f
  float* ego2   = ego1 + (size_t)N_NODE * DIM;          // 5.12M f
  float* proj   = ego2 + (size_t)N_NODE * DIM;          // 5.12M f
  int*   tperm  = (int*)(proj + (size_t)N_NODE * DIM);  // 640K i
  float* vperm  = (float*)(tperm + N_EDGES);            // 640K f
  int*   cnt    = (int*)(vperm + N_EDGES);              // 40K i
  int*   rowptr = cnt + N_NODE;                         // 40001 i (padded)
  int*   bsum   = rowptr + N_NODE + 64;                 // 256 i
  // overlays (lifetimes disjoint):
  int*   ipos   = (int*)ego2;   // dead before spmm2 writes ego2
  float* tmpK   = proj;         // dead before local_agg

  float* out_hidden = (float*)d_out;
  float* out_node   = out_hidden + (size_t)BS * SQ * DIM;

  // ---- CSR build ----
  hipMemsetAsync(cnt, 0, N_NODE * sizeof(int), stream);
  hist_kernel<<<N_EDGES / 256, 256, 0, stream>>>(hl, cnt);
  bsum_kernel<<<NB, 256, 0, stream>>>(cnt, bsum);
  scan_bsum_kernel<<<1, 256, 0, stream>>>(bsum);
  scan_final_kernel<<<NB, 256, 0, stream>>>(cnt, bsum, rowptr);
  scatter_kernel<<<N_EDGES / 256, 256, 0, stream>>>(hl, tl, ain, rowptr, cnt,
                                                    ipos, tperm, vperm);

  // ---- hop 0: ego1 = spmm(a_in, h, t, embedding) ----
  spmm_csr<<<(N_NODE * 64) / 256, 256, 0, stream>>>(emb, vperm, tperm, rowptr, ego1);

  // ---- update_attention ----
  for (int r = 0; r < N_REL; r++) {
    proj_gemm<<<N_NODE / 64, 256, 0, stream>>>(ego1, transM + (size_t)r * DIM * DIM, proj);
    edge_attn<<<PER_REL / 4, 256, 0, stream>>>(proj, hl, tl, rembw + r * DIM,
                                               ipos, vperm, r * PER_REL);
  }

  // ---- row softmax (in place, normalized) ----
  rowsoftmax<<<(N_NODE * 64) / 256, 256, 0, stream>>>(rowptr, vperm);

  // ---- hop 1: ego2 = spmm(softmax(vnew), h, t, ego1) ----
  spmm_csr<<<(N_NODE * 64) / 256, 256, 0, stream>>>(ego1, vperm, tperm, rowptr, ego2);

  // ---- session-local double attention ----
  local_agg2<<<BS * 2, 512, 0, stream>>>(emb, ego1, ego2, inputs, Aadj,
                                         a0, a1, a2, a3, out_hidden, out_node, tmpK);
  add_kernel<<<(BS * SQ * DIM / 4) / 256, 256, 0, stream>>>(out_hidden, tmpK);
}

// Round 4
// 604.964 us; speedup vs baseline: 5.4305x; 1.3714x over previous
//
#include <hip/hip_runtime.h>

#define N_NODE  40000
#define DIM     128
#define N_REL   8
#define N_EDGES 640000
#define PER_REL (N_EDGES / N_REL)
#define BS      128
#define SQ      50
#define NB      ((N_NODE + 255) / 256)   // 157 scan blocks

typedef unsigned int   u32;
typedef unsigned short u16;
typedef short  bf16x8 __attribute__((ext_vector_type(8)));
typedef float  f32x4  __attribute__((ext_vector_type(4)));

__device__ __forceinline__ u16 f2bf(float f) {
  union { float f; u32 i; } c; c.f = f;
  u32 b = c.i;
  b += 0x7FFFu + ((b >> 16) & 1u);   // RNE
  return (u16)(b >> 16);
}
__device__ __forceinline__ float bf2f(u32 u) {
  union { u32 i; float f; } c; c.i = u << 16; return c.f;
}
__device__ __forceinline__ float tanh_fast(float x) {
  // tanh(x) = 1 - 2/(exp(2x)+1)
  return 1.f - 2.f / (__expf(2.f * x) + 1.f);
}

// ==================================================================
// CSR build: histogram -> exclusive scan -> scatter
// ==================================================================
__global__ void hist_kernel(const int* __restrict__ hl, int* __restrict__ cnt) {
  int e = blockIdx.x * 256 + threadIdx.x;
  if (e < N_EDGES) atomicAdd(&cnt[hl[e]], 1);
}

__global__ void bsum_kernel(const int* __restrict__ cnt, int* __restrict__ bsum) {
  __shared__ int sd[256];
  int i = blockIdx.x * 256 + threadIdx.x;
  sd[threadIdx.x] = (i < N_NODE) ? cnt[i] : 0;
  __syncthreads();
  for (int o = 128; o; o >>= 1) {
    if (threadIdx.x < o) sd[threadIdx.x] += sd[threadIdx.x + o];
    __syncthreads();
  }
  if (!threadIdx.x) bsum[blockIdx.x] = sd[0];
}

__global__ void scan_bsum_kernel(int* __restrict__ bsum) {   // single block, NB<=256
  __shared__ int sd[256];
  int t = threadIdx.x;
  int orig = (t < NB) ? bsum[t] : 0;
  sd[t] = orig;
  __syncthreads();
  for (int o = 1; o < 256; o <<= 1) {
    int v = (t >= o) ? sd[t - o] : 0;
    __syncthreads();
    sd[t] += v;
    __syncthreads();
  }
  if (t < NB) bsum[t] = sd[t] - orig;   // exclusive
}

__global__ void scan_final_kernel(const int* __restrict__ cnt, const int* __restrict__ bsum,
                                  int* __restrict__ rowptr) {
  __shared__ int sd[256];
  int t = threadIdx.x;
  int i = blockIdx.x * 256 + t;
  int orig = (i < N_NODE) ? cnt[i] : 0;
  sd[t] = orig;
  __syncthreads();
  for (int o = 1; o < 256; o <<= 1) {
    int v = (t >= o) ? sd[t - o] : 0;
    __syncthreads();
    sd[t] += v;
    __syncthreads();
  }
  int ex = sd[t] - orig + bsum[blockIdx.x];
  if (i < N_NODE) {
    rowptr[i] = ex;
    if (i == N_NODE - 1) rowptr[N_NODE] = ex + orig;
  }
}

__global__ void scatter_kernel(const int* __restrict__ hl, const int* __restrict__ tl,
                               const float* __restrict__ ain, const int* __restrict__ rowptr,
                               int* __restrict__ cnt, int* __restrict__ ipos,
                               int* __restrict__ tperm, float* __restrict__ vperm) {
  int e = blockIdx.x * 256 + threadIdx.x;
  if (e >= N_EDGES) return;
  int hn = hl[e];
  int c = atomicSub(&cnt[hn], 1);            // old value: count..1
  int pos = rowptr[hn + 1] - c;
  ipos[e] = pos;
  tperm[pos] = tl[e];
  vperm[pos] = ain[e];
}

// ==================================================================
// CSR spmm: out[r] = sum_{p in row r} vals[p] * x[tperm[p]]
// ==================================================================
__global__ void __launch_bounds__(256)
spmm_csr(const float* __restrict__ x, const float* __restrict__ vals,
         const int* __restrict__ tperm, const int* __restrict__ rowptr,
         float* __restrict__ out) {
  int row = (blockIdx.x * 256 + threadIdx.x) >> 6;
  if (row >= N_NODE) return;
  int lane = threadIdx.x & 63;
  int lo = rowptr[row], n = rowptr[row + 1] - lo;
  float ax = 0.f, ay = 0.f;
  const float* xb = x + 2 * lane;
  int p = 0;
  for (; p + 1 < n; p += 2) {
    int   t0 = tperm[lo + p],     t1 = tperm[lo + p + 1];
    float v0 = vals[lo + p],      v1 = vals[lo + p + 1];
    float2 x0 = *reinterpret_cast<const float2*>(xb + (size_t)t0 * DIM);
    float2 x1 = *reinterpret_cast<const float2*>(xb + (size_t)t1 * DIM);
    ax += v0 * x0.x + v1 * x1.x;
    ay += v0 * x0.y + v1 * x1.y;
  }
  if (p < n) {
    int   t0 = tperm[lo + p];
    float v0 = vals[lo + p];
    float2 x0 = *reinterpret_cast<const float2*>(xb + (size_t)t0 * DIM);
    ax += v0 * x0.x;
    ay += v0 * x0.y;
  }
  float2 r; r.x = ax; r.y = ay;
  *reinterpret_cast<float2*>(out + (size_t)row * DIM + 2 * lane) = r;
}

// ==================================================================
// proj_bf16 = bf16( ego(40000x128) @ W_r(128x128) )  via MFMA 16x16x32 bf16
// block: 128 nodes x 128 cols, 4 waves; wave w owns rows 32w..32w+31.
// LDS XOR-swizzle (T2): byte ^= ((row&7)<<4). k-permutation-invariant frags.
// ==================================================================
__global__ void __launch_bounds__(256)
proj_mfma(const float* __restrict__ ego, const float* __restrict__ Wg,
          u16* __restrict__ projb) {
  __shared__ u16 Al[128 * 128];   // logical [m][k] bf16, swizzled
  __shared__ u16 Bt[128 * 128];   // logical [n][k] bf16 (W transposed), swizzled
  int tid = threadIdx.x;
  int gbase = blockIdx.x * 128;

  // stage A (ego rows -> bf16, swizzled)
  for (int x = tid; x < 4096; x += 256) {
    int m  = x >> 5;
    int kq = (x & 31) << 2;
    int gm = gbase + m; if (gm >= N_NODE) gm = N_NODE - 1;
    float4 v = *reinterpret_cast<const float4*>(ego + (size_t)gm * DIM + kq);
    int byte = (m * 256 + kq * 2) ^ ((m & 7) << 4);
    u32* p = reinterpret_cast<u32*>(reinterpret_cast<char*>(Al) + byte);
    p[0] = (u32)f2bf(v.x) | ((u32)f2bf(v.y) << 16);
    p[1] = (u32)f2bf(v.z) | ((u32)f2bf(v.w) << 16);
  }
  // stage W transposed (read coalesced in n, scatter u16 into [n][k])
  for (int x = tid; x < 4096; x += 256) {
    int k  = x >> 5;
    int nq = (x & 31) << 2;
    float4 v = *reinterpret_cast<const float4*>(Wg + k * DIM + nq);
    float fv[4] = {v.x, v.y, v.z, v.w};
    #pragma unroll
    for (int j = 0; j < 4; j++) {
      int n = nq + j;
      int byte = (n * 256 + k * 2) ^ ((n & 7) << 4);
      *reinterpret_cast<u16*>(reinterpret_cast<char*>(Bt) + byte) = f2bf(fv[j]);
    }
  }
  __syncthreads();

  int w = tid >> 6, lane = tid & 63;
  int l15 = lane & 15, g = lane >> 4;
  f32x4 acc[2][8];
  #pragma unroll
  for (int mt = 0; mt < 2; mt++)
    #pragma unroll
    for (int nt = 0; nt < 8; nt++) acc[mt][nt] = (f32x4){0.f, 0.f, 0.f, 0.f};

  #pragma unroll
  for (int kk = 0; kk < 4; kk++) {
    int kb = (kk * 32 + g * 8) * 2;           // byte offset of this lane's k-run
    bf16x8 a[2];
    #pragma unroll
    for (int mt = 0; mt < 2; mt++) {
      int m = w * 32 + mt * 16 + l15;
      int byte = (m * 256 + kb) ^ ((m & 7) << 4);
      a[mt] = *reinterpret_cast<bf16x8*>(reinterpret_cast<char*>(Al) + byte);
    }
    #pragma unroll
    for (int nt = 0; nt < 8; nt++) {
      int n = nt * 16 + l15;
      int byte = (n * 256 + kb) ^ ((n & 7) << 4);
      bf16x8 b = *reinterpret_cast<bf16x8*>(reinterpret_cast<char*>(Bt) + byte);
      acc[0][nt] = __builtin_amdgcn_mfma_f32_16x16x32_bf16(a[0], b, acc[0][nt], 0, 0, 0);
      acc[1][nt] = __builtin_amdgcn_mfma_f32_16x16x32_bf16(a[1], b, acc[1][nt], 0, 0, 0);
    }
  }
  // C/D: col = lane&15, row = (lane>>4)*4 + reg   [m89-verified]
  #pragma unroll
  for (int mt = 0; mt < 2; mt++) {
    #pragma unroll
    for (int reg = 0; reg < 4; reg++) {
      int node = gbase + w * 32 + mt * 16 + g * 4 + reg;
      if (node < N_NODE) {
        #pragma unroll
        for (int nt = 0; nt < 8; nt++)
          projb[(size_t)node * DIM + nt * 16 + l15] = f2bf(acc[mt][nt][reg]);
      }
    }
  }
}

// ==================================================================
// vnew[ipos[e]] = sum_d tanh(proj[t]) * proj[h] + sum_d r_emb   (bf16 proj)
// ==================================================================
__global__ void edge_attn(const u16* __restrict__ projb, const int* __restrict__ hl,
                          const int* __restrict__ tl, const float* __restrict__ remb,
                          const int* __restrict__ ipos, float* __restrict__ vperm,
                          int ebase) {
  int lane = threadIdx.x & 63;
  int e = ebase + blockIdx.x * 4 + (threadIdx.x >> 6);
  int hn = hl[e], tn = tl[e];
  u32 wh = *reinterpret_cast<const u32*>(projb + (size_t)hn * DIM + 2 * lane);
  u32 wt = *reinterpret_cast<const u32*>(projb + (size_t)tn * DIM + 2 * lane);
  float2 rv = *reinterpret_cast<const float2*>(remb + 2 * lane);
  float s = tanh_fast(bf2f(wt & 0xffffu)) * bf2f(wh & 0xffffu)
          + tanh_fast(bf2f(wt >> 16))     * bf2f(wh >> 16)
          + rv.x + rv.y;
  #pragma unroll
  for (int off = 32; off; off >>= 1) s += __shfl_xor(s, off, 64);
  if (lane == 0) vperm[ipos[e]] = s;
}

// ==================================================================
// per-row softmax over CSR segment, 2-pass (shift-invariant, |v|<~6)
// ==================================================================
__global__ void __launch_bounds__(256)
rowsoftmax(const int* __restrict__ rowptr, float* __restrict__ v) {
  int row = (blockIdx.x * 256 + threadIdx.x) >> 6;
  if (row >= N_NODE) return;
  int lane = threadIdx.x & 63;
  int lo = rowptr[row], n = rowptr[row + 1] - lo;
  if (n == 0) return;
  float s = 0.f;
  for (int p = lane; p < n; p += 64) {
    float ex = __expf(v[lo + p]);
    v[lo + p] = ex;
    s += ex;
  }
  #pragma unroll
  for (int o = 32; o; o >>= 1) s += __shfl_xor(s, o, 64);
  float inv = 1.f / s;
  for (int p = lane; p < n; p += 64) v[lo + p] *= inv;
}

// ==================================================================
// local_agg: block = (b, which); adj staged in LDS; no-max softmax.
// ==================================================================
__global__ void __launch_bounds__(512)
local_agg3(const float* __restrict__ emb, const float* __restrict__ ego1,
           const float* __restrict__ ego2, const int* __restrict__ inp,
           const int* __restrict__ Aadj,
           const float* __restrict__ a0, const float* __restrict__ a1,
           const float* __restrict__ a2, const float* __restrict__ a3,
           float* __restrict__ out_hidden, float* __restrict__ out_node,
           float* __restrict__ tmpK) {
  __shared__ float h[SQ][DIM];    // 25.6 KB
  __shared__ float aS[4][DIM];    // 2 KB
  __shared__ int   adjL[SQ * SQ]; // 10 KB
  int b = blockIdx.x >> 1, which = blockIdx.x & 1;
  int tid = threadIdx.x;
  if (tid < 4 * DIM) {
    int kk = tid >> 7, d = tid & 127;
    const float* ap = (kk == 0) ? a0 : (kk == 1) ? a1 : (kk == 2) ? a2 : a3;
    aS[kk][d] = ap[d];
  }
  for (int x = tid; x < SQ * SQ; x += 512) adjL[x] = Aadj[b * SQ * SQ + x];
  for (int x = tid; x < SQ * DIM; x += 512) {
    int s = x >> 7, d = x & 127;
    int node = inp[b * SQ + s];
    if (which == 0) {
      float uv = emb[(size_t)node * DIM + d];
      h[s][d] = uv;
      out_node[(size_t)(b * SQ + s) * DIM + d] = uv;
    } else {
      h[s][d] = 0.5f * (ego1[(size_t)node * DIM + d] + ego2[(size_t)node * DIM + d]);
    }
  }
  __syncthreads();
  int wv = tid >> 6, lane = tid & 63;
  float* dst = (which == 0) ? out_hidden : tmpK;
  for (int i = wv; i < SQ; i += 8) {
    int d0 = lane, d1 = lane + 64;
    float hi0 = h[i][d0], hi1 = h[i][d1];
    float sden = 0.f, o0 = 0.f, o1 = 0.f;
    for (int j = 0; j < SQ; j++) {
      int ad = adjL[i * SQ + j];               // LDS broadcast, wave-uniform
      float hj0 = h[j][d0], hj1 = h[j][d1];
      if (ad > 0) {                            // uniform branch
        float A0 = aS[ad - 1][d0], A1 = aS[ad - 1][d1];
        float p0 = hi0 * hj0; p0 = p0 > 0.f ? p0 : 0.2f * p0;
        float p1 = hi1 * hj1; p1 = p1 > 0.f ? p1 : 0.2f * p1;
        float ee = p0 * A0 + p1 * A1;
        #pragma unroll
        for (int off = 32; off; off >>= 1) ee += __shfl_xor(ee, off, 64);
        float p = __expf(ee);                  // no max shift: logits bounded
        sden += p;
        o0 += p * hj0;
        o1 += p * hj1;
      }
    }
    float inv = (sden > 0.f) ? 1.f / sden : 0.f;
    dst[(size_t)(b * SQ + i) * DIM + d0] = o0 * inv;
    dst[(size_t)(b * SQ + i) * DIM + d1] = o1 * inv;
  }
}

__global__ void add_kernel(float* __restrict__ out, const float* __restrict__ add) {
  int i = blockIdx.x * 256 + threadIdx.x;
  float4 a = reinterpret_cast<const float4*>(add)[i];
  float4 o = reinterpret_cast<float4*>(out)[i];
  o.x += a.x; o.y += a.y; o.z += a.z; o.w += a.w;
  reinterpret_cast<float4*>(out)[i] = o;
}

// ==================================================================
extern "C" void kernel_launch(void* const* d_in, const int* in_sizes, int n_in,
                              void* d_out, int out_size, void* d_ws, size_t ws_size,
                              hipStream_t stream) {
  const int*   inputs = (const int*)d_in[0];
  const int*   Aadj   = (const int*)d_in[1];
  const float* emb    = (const float*)d_in[3];
  const float* rembw  = (const float*)d_in[4];
  const float* transM = (const float*)d_in[5];
  const float* a0     = (const float*)d_in[6];
  const float* a1     = (const float*)d_in[7];
  const float* a2     = (const float*)d_in[8];
  const float* a3     = (const float*)d_in[9];
  const float* ain    = (const float*)d_in[10];
  const int*   hl     = (const int*)d_in[11];
  const int*   tl     = (const int*)d_in[12];

  // workspace layout (<= 66.9 MB proven footprint):
  float* ego1   = (float*)d_ws;                         // 5.12M f
  float* ego2   = ego1 + (size_t)N_NODE * DIM;          // 5.12M f
  float* proj   = ego2 + (size_t)N_NODE * DIM;          // 5.12M f region (bf16 uses half)
  int*   tperm  = (int*)(proj + (size_t)N_NODE * DIM);  // 640K i
  float* vperm  = (float*)(tperm + N_EDGES);            // 640K f
  int*   cnt    = (int*)(vperm + N_EDGES);              // 40K i
  int*   rowptr = cnt + N_NODE;                         // 40001 i (padded)
  int*   bsum   = rowptr + N_NODE + 64;                 // 256 i
  u16*   projb  = (u16*)proj;
  // overlays (lifetimes disjoint):
  int*   ipos   = (int*)ego2;   // dead before spmm2 writes ego2
  float* tmpK   = proj;         // dead before local_agg

  float* out_hidden = (float*)d_out;
  float* out_node   = out_hidden + (size_t)BS * SQ * DIM;

  // ---- CSR build ----
  hipMemsetAsync(cnt, 0, N_NODE * sizeof(int), stream);
  hist_kernel<<<N_EDGES / 256, 256, 0, stream>>>(hl, cnt);
  bsum_kernel<<<NB, 256, 0, stream>>>(cnt, bsum);
  scan_bsum_kernel<<<1, 256, 0, stream>>>(bsum);
  scan_final_kernel<<<NB, 256, 0, stream>>>(cnt, bsum, rowptr);
  scatter_kernel<<<N_EDGES / 256, 256, 0, stream>>>(hl, tl, ain, rowptr, cnt,
                                                    ipos, tperm, vperm);

  // ---- hop 0: ego1 = spmm(a_in, h, t, embedding) ----
  spmm_csr<<<(N_NODE * 64) / 256, 256, 0, stream>>>(emb, vperm, tperm, rowptr, ego1);

  // ---- update_attention: MFMA projection + edge scoring per relation ----
  for (int r = 0; r < N_REL; r++) {
    proj_mfma<<<(N_NODE + 127) / 128, 256, 0, stream>>>(
        ego1, transM + (size_t)r * DIM * DIM, projb);
    edge_attn<<<PER_REL / 4, 256, 0, stream>>>(projb, hl, tl, rembw + r * DIM,
                                               ipos, vperm, r * PER_REL);
  }

  // ---- row softmax (in place, normalized) ----
  rowsoftmax<<<(N_NODE * 64) / 256, 256, 0, stream>>>(rowptr, vperm);

  // ---- hop 1: ego2 = spmm(softmax(vnew), h, t, ego1) ----
  spmm_csr<<<(N_NODE * 64) / 256, 256, 0, stream>>>(ego1, vperm, tperm, rowptr, ego2);

  // ---- session-local double attention ----
  local_agg3<<<BS * 2, 512, 0, stream>>>(emb, ego1, ego2, inputs, Aadj,
                                         a0, a1, a2, a3, out_hidden, out_node, tmpK);
  add_kernel<<<(BS * SQ * DIM / 4) / 256, 256, 0, stream>>>(out_hidden, tmpK);
}

// Round 5
// 484.966 us; speedup vs baseline: 6.7742x; 1.2474x over previous
//
#include <hip/hip_runtime.h>

#define N_NODE  40000
#define DIM     128
#define N_REL   8
#define N_EDGES 640000
#define PER_REL (N_EDGES / N_REL)
#define BS      128
#define SQ      50
#define NB      ((N_NODE + 255) / 256)   // 157 scan blocks

typedef unsigned int   u32;
typedef unsigned short u16;
typedef short  bf16x8 __attribute__((ext_vector_type(8)));
typedef float  f32x4  __attribute__((ext_vector_type(4)));

__device__ __forceinline__ u16 f2bf(float f) {
  union { float f; u32 i; } c; c.f = f;
  u32 b = c.i;
  b += 0x7FFFu + ((b >> 16) & 1u);   // RNE
  return (u16)(b >> 16);
}
__device__ __forceinline__ float bf2f(u32 u) {
  union { u32 i; float f; } c; c.i = u << 16; return c.f;
}
__device__ __forceinline__ u32 pk2(float a, float b) {
  return (u32)f2bf(a) | ((u32)f2bf(b) << 16);
}
__device__ __forceinline__ float tanh_fast(float x) {
  return 1.f - 2.f / (__expf(2.f * x) + 1.f);
}

// ==================================================================
// CSR build
// ==================================================================
__global__ void hist_kernel(const int* __restrict__ hl, int* __restrict__ cnt) {
  int e = blockIdx.x * 256 + threadIdx.x;
  if (e < N_EDGES) atomicAdd(&cnt[hl[e]], 1);
}

__global__ void bsum_kernel(const int* __restrict__ cnt, int* __restrict__ bsum) {
  __shared__ int sd[256];
  int i = blockIdx.x * 256 + threadIdx.x;
  sd[threadIdx.x] = (i < N_NODE) ? cnt[i] : 0;
  __syncthreads();
  for (int o = 128; o; o >>= 1) {
    if (threadIdx.x < o) sd[threadIdx.x] += sd[threadIdx.x + o];
    __syncthreads();
  }
  if (!threadIdx.x) bsum[blockIdx.x] = sd[0];
}

__global__ void scan_bsum_kernel(int* __restrict__ bsum) {
  __shared__ int sd[256];
  int t = threadIdx.x;
  int orig = (t < NB) ? bsum[t] : 0;
  sd[t] = orig;
  __syncthreads();
  for (int o = 1; o < 256; o <<= 1) {
    int v = (t >= o) ? sd[t - o] : 0;
    __syncthreads();
    sd[t] += v;
    __syncthreads();
  }
  if (t < NB) bsum[t] = sd[t] - orig;
}

__global__ void scan_final_kernel(const int* __restrict__ cnt, const int* __restrict__ bsum,
                                  int* __restrict__ rowptr) {
  __shared__ int sd[256];
  int t = threadIdx.x;
  int i = blockIdx.x * 256 + t;
  int orig = (i < N_NODE) ? cnt[i] : 0;
  sd[t] = orig;
  __syncthreads();
  for (int o = 1; o < 256; o <<= 1) {
    int v = (t >= o) ? sd[t - o] : 0;
    __syncthreads();
    sd[t] += v;
    __syncthreads();
  }
  int ex = sd[t] - orig + bsum[blockIdx.x];
  if (i < N_NODE) {
    rowptr[i] = ex;
    if (i == N_NODE - 1) rowptr[N_NODE] = ex + orig;
  }
}

__global__ void scatter_kernel(const int* __restrict__ hl, const int* __restrict__ tl,
                               const float* __restrict__ ain, const int* __restrict__ rowptr,
                               int* __restrict__ cnt, int* __restrict__ ipos,
                               int* __restrict__ tperm, float* __restrict__ vperm) {
  int e = blockIdx.x * 256 + threadIdx.x;
  if (e >= N_EDGES) return;
  int hn = hl[e];
  int c = atomicSub(&cnt[hn], 1);
  int pos = rowptr[hn + 1] - c;
  ipos[e] = pos;
  tperm[pos] = tl[e];
  vperm[pos] = ain[e];
}

// ==================================================================
// f32 -> packed bf16 conversion (embedding)
// ==================================================================
__global__ void conv_bf16(const float* __restrict__ in, u32* __restrict__ out) {
  int i = blockIdx.x * 256 + threadIdx.x;
  float2 v = reinterpret_cast<const float2*>(in)[i];
  out[i] = pk2(v.x, v.y);
}

// ==================================================================
// CSR spmm on packed-bf16 features: out[r] = sum vals[p]*x[tperm[p]]
// one wave/row, lane owns dims {2l, 2l+1}; f32 accumulate, bf16 out
// ==================================================================
__global__ void __launch_bounds__(256)
spmm_csr_b(const u32* __restrict__ xb, const float* __restrict__ vals,
           const int* __restrict__ tperm, const int* __restrict__ rowptr,
           u32* __restrict__ outb) {
  int row = (blockIdx.x * 256 + threadIdx.x) >> 6;
  if (row >= N_NODE) return;
  int lane = threadIdx.x & 63;
  int lo = rowptr[row], n = rowptr[row + 1] - lo;
  float ax = 0.f, ay = 0.f;
  const u32* xl = xb + lane;
  int p = 0;
  for (; p + 1 < n; p += 2) {
    int   t0 = tperm[lo + p], t1 = tperm[lo + p + 1];
    float v0 = vals[lo + p],  v1 = vals[lo + p + 1];
    u32 w0 = xl[(size_t)t0 << 6], w1 = xl[(size_t)t1 << 6];
    ax += v0 * bf2f(w0 & 0xffffu) + v1 * bf2f(w1 & 0xffffu);
    ay += v0 * bf2f(w0 >> 16)     + v1 * bf2f(w1 >> 16);
  }
  if (p < n) {
    int   t0 = tperm[lo + p];
    float v0 = vals[lo + p];
    u32 w0 = xl[(size_t)t0 << 6];
    ax += v0 * bf2f(w0 & 0xffffu);
    ay += v0 * bf2f(w0 >> 16);
  }
  outb[((size_t)row << 6) + lane] = pk2(ax, ay);
}

// ==================================================================
// projb = bf16( ego(bf16) @ W_r ) via MFMA 16x16x32 bf16 (R4-proven maps)
// ==================================================================
__global__ void __launch_bounds__(256)
proj_mfma(const u32* __restrict__ egob, const float* __restrict__ Wg,
          u16* __restrict__ projb) {
  __shared__ u16 Al[128 * 128];   // [m][k] swizzled
  __shared__ u16 Bt[128 * 128];   // [n][k] swizzled
  int tid = threadIdx.x;
  int gbase = blockIdx.x * 128;

  for (int x = tid; x < 128 * 64; x += 256) {   // A: straight packed copy
    int m = x >> 6, d2 = x & 63;
    int gm = gbase + m; if (gm >= N_NODE) gm = N_NODE - 1;
    u32 v = egob[((size_t)gm << 6) + d2];
    int byte = (m * 256 + d2 * 4) ^ ((m & 7) << 4);
    *reinterpret_cast<u32*>(reinterpret_cast<char*>(Al) + byte) = v;
  }
  for (int x = tid; x < 4096; x += 256) {       // W transposed -> [n][k]
    int k  = x >> 5;
    int nq = (x & 31) << 2;
    float4 v = *reinterpret_cast<const float4*>(Wg + k * DIM + nq);
    float fv[4] = {v.x, v.y, v.z, v.w};
    #pragma unroll
    for (int j = 0; j < 4; j++) {
      int n = nq + j;
      int byte = (n * 256 + k * 2) ^ ((n & 7) << 4);
      *reinterpret_cast<u16*>(reinterpret_cast<char*>(Bt) + byte) = f2bf(fv[j]);
    }
  }
  __syncthreads();

  int w = tid >> 6, lane = tid & 63;
  int l15 = lane & 15, g = lane >> 4;
  f32x4 acc[2][8];
  #pragma unroll
  for (int mt = 0; mt < 2; mt++)
    #pragma unroll
    for (int nt = 0; nt < 8; nt++) acc[mt][nt] = (f32x4){0.f, 0.f, 0.f, 0.f};

  #pragma unroll
  for (int kk = 0; kk < 4; kk++) {
    int kb = (kk * 32 + g * 8) * 2;
    bf16x8 a[2];
    #pragma unroll
    for (int mt = 0; mt < 2; mt++) {
      int m = w * 32 + mt * 16 + l15;
      int byte = (m * 256 + kb) ^ ((m & 7) << 4);
      a[mt] = *reinterpret_cast<bf16x8*>(reinterpret_cast<char*>(Al) + byte);
    }
    #pragma unroll
    for (int nt = 0; nt < 8; nt++) {
      int n = nt * 16 + l15;
      int byte = (n * 256 + kb) ^ ((n & 7) << 4);
      bf16x8 b = *reinterpret_cast<bf16x8*>(reinterpret_cast<char*>(Bt) + byte);
      acc[0][nt] = __builtin_amdgcn_mfma_f32_16x16x32_bf16(a[0], b, acc[0][nt], 0, 0, 0);
      acc[1][nt] = __builtin_amdgcn_mfma_f32_16x16x32_bf16(a[1], b, acc[1][nt], 0, 0, 0);
    }
  }
  #pragma unroll
  for (int mt = 0; mt < 2; mt++) {
    #pragma unroll
    for (int reg = 0; reg < 4; reg++) {
      int node = gbase + w * 32 + mt * 16 + g * 4 + reg;
      if (node < N_NODE) {
        #pragma unroll
        for (int nt = 0; nt < 8; nt++)
          projb[(size_t)node * DIM + nt * 16 + l15] = f2bf(acc[mt][nt][reg]);
      }
    }
  }
}

// ==================================================================
// edge scores (bf16 proj), one wave/edge
// ==================================================================
__global__ void edge_attn(const u16* __restrict__ projb, const int* __restrict__ hl,
                          const int* __restrict__ tl, const float* __restrict__ remb,
                          const int* __restrict__ ipos, float* __restrict__ vperm,
                          int ebase) {
  int lane = threadIdx.x & 63;
  int e = ebase + blockIdx.x * 4 + (threadIdx.x >> 6);
  int hn = hl[e], tn = tl[e];
  u32 wh = *reinterpret_cast<const u32*>(projb + (size_t)hn * DIM + 2 * lane);
  u32 wt = *reinterpret_cast<const u32*>(projb + (size_t)tn * DIM + 2 * lane);
  float2 rv = *reinterpret_cast<const float2*>(remb + 2 * lane);
  float s = tanh_fast(bf2f(wt & 0xffffu)) * bf2f(wh & 0xffffu)
          + tanh_fast(bf2f(wt >> 16))     * bf2f(wh >> 16)
          + rv.x + rv.y;
  #pragma unroll
  for (int off = 32; off; off >>= 1) s += __shfl_xor(s, off, 64);
  if (lane == 0) vperm[ipos[e]] = s;
}

// ==================================================================
// per-row softmax over CSR segment, 2-pass, in place
// ==================================================================
__global__ void __launch_bounds__(256)
rowsoftmax(const int* __restrict__ rowptr, float* __restrict__ v) {
  int row = (blockIdx.x * 256 + threadIdx.x) >> 6;
  if (row >= N_NODE) return;
  int lane = threadIdx.x & 63;
  int lo = rowptr[row], n = rowptr[row + 1] - lo;
  if (n == 0) return;
  float s = 0.f;
  for (int p = lane; p < n; p += 64) {
    float ex = __expf(v[lo + p]);
    v[lo + p] = ex;
    s += ex;
  }
  #pragma unroll
  for (int o = 32; o; o >>= 1) s += __shfl_xor(s, o, 64);
  float inv = 1.f / s;
  for (int p = lane; p < n; p += 64) v[lo + p] *= inv;
}

// ==================================================================
// local_agg via MFMA:
//   LeakyReLU(x*y) = 0.6*x*y + 0.4*|x|*|y|
//   Q = [h, |h|] (50x256 bf16);  S_k = (Q . c_k) @ Q^T,  c_k=[.6 a_k, .4 a_k]
//   P[i][j] = exp(S_{adj-1}[i][j]) masked;  out = (P @ h) * 1/rowsum
// block = (b, which); 512 threads = 8 waves.
// ==================================================================
__global__ void __launch_bounds__(512)
local_agg4(const float* __restrict__ emb, const u32* __restrict__ ego1b,
           const u32* __restrict__ ego2b, const int* __restrict__ inp,
           const int* __restrict__ Aadj,
           const float* __restrict__ a0, const float* __restrict__ a1,
           const float* __restrict__ a2, const float* __restrict__ a3,
           float* __restrict__ out_hidden, float* __restrict__ out_node,
           float* __restrict__ tmpK) {
  __shared__ u16   Qb[64 * 256];     // 32 KB  [m][kk] swz, rows>=50 garbage(ok)
  __shared__ u16   hTb[128 * 64];    // 16 KB  [d][j]  swz, cols>=50 zeroed
  __shared__ float aC[4][256];       // 4 KB
  __shared__ float S[4][64 * 66];    // 67.6 KB  padded
  __shared__ u16   P[64 * 64];       // 8 KB   [i][j] swz
  __shared__ float sinv[64];
  __shared__ int   adjL[SQ * SQ];    // 10 KB

  int b = blockIdx.x >> 1, which = blockIdx.x & 1;
  int tid = threadIdx.x;

  { // c vectors
    int k = tid >> 7, d = tid & 127;
    const float* ap = (k == 0) ? a0 : (k == 1) ? a1 : (k == 2) ? a2 : a3;
    float av = ap[d];
    aC[k][d] = 0.6f * av;
    aC[k][128 + d] = 0.4f * av;
  }
  for (int x = tid; x < SQ * SQ; x += 512) adjL[x] = Aadj[b * SQ * SQ + x];
  for (int x = tid; x < 128 * 16; x += 512) {   // zero hTb cols 50..63
    int d = x >> 4, j = 48 + (x & 15);
    if (j >= 50) {
      int byte = (d * 128 + j * 2) ^ ((d & 7) << 4);
      *reinterpret_cast<u16*>(reinterpret_cast<char*>(hTb) + byte) = 0;
    }
  }
  for (int x = tid; x < SQ * 64; x += 512) {    // stage h (+|h|, +h^T)
    int j = x >> 6, d2 = (x & 63) << 1;
    int node = inp[b * SQ + j];
    float v0, v1;
    if (which == 0) {
      float2 vv = *reinterpret_cast<const float2*>(emb + (size_t)node * DIM + d2);
      v0 = vv.x; v1 = vv.y;
      *reinterpret_cast<float2*>(out_node + (size_t)(b * SQ + j) * DIM + d2) = vv;
    } else {
      u32 w1 = ego1b[((size_t)node << 6) + (d2 >> 1)];
      u32 w2 = ego2b[((size_t)node << 6) + (d2 >> 1)];
      v0 = 0.5f * (bf2f(w1 & 0xffffu) + bf2f(w2 & 0xffffu));
      v1 = 0.5f * (bf2f(w1 >> 16) + bf2f(w2 >> 16));
    }
    u16 b0 = f2bf(v0), b1 = f2bf(v1);
    { int byte = (j * 512 + d2 * 2) ^ ((j & 7) << 4);
      *reinterpret_cast<u32*>(reinterpret_cast<char*>(Qb) + byte) = (u32)b0 | ((u32)b1 << 16); }
    { int byte = (j * 512 + 256 + d2 * 2) ^ ((j & 7) << 4);
      u32 m0 = b0 & 0x7fffu, m1 = b1 & 0x7fffu;
      *reinterpret_cast<u32*>(reinterpret_cast<char*>(Qb) + byte) = m0 | (m1 << 16); }
    { int byte = (d2 * 128 + j * 2) ^ ((d2 & 7) << 4);
      *reinterpret_cast<u16*>(reinterpret_cast<char*>(hTb) + byte) = b0; }
    { int byte = ((d2 + 1) * 128 + j * 2) ^ (((d2 + 1) & 7) << 4);
      *reinterpret_cast<u16*>(reinterpret_cast<char*>(hTb) + byte) = b1; }
  }
  __syncthreads();

  int w = tid >> 6, lane = tid & 63;
  int l15 = lane & 15, g = lane >> 4;

  { // ---- S-phase: wave = k*2+half ----
    int k = w >> 1, half = w & 1;
    const float* aCk = aC[k];
    f32x4 acc[2][4];
    #pragma unroll
    for (int mt = 0; mt < 2; mt++)
      #pragma unroll
      for (int nt = 0; nt < 4; nt++) acc[mt][nt] = (f32x4){0.f, 0.f, 0.f, 0.f};
    for (int ks = 0; ks < 8; ks++) {
      int kb = ks * 32 + g * 8;
      float4 c01 = *reinterpret_cast<const float4*>(aCk + kb);
      float4 c23 = *reinterpret_cast<const float4*>(aCk + kb + 4);
      bf16x8 afr[2];
      #pragma unroll
      for (int mt = 0; mt < 2; mt++) {
        int m = (half * 2 + mt) * 16 + l15;
        int byte = (m * 512 + kb * 2) ^ ((m & 7) << 4);
        union { bf16x8 v; u32 u[4]; } q, o;
        q.v = *reinterpret_cast<bf16x8*>(reinterpret_cast<char*>(Qb) + byte);
        o.u[0] = pk2(bf2f(q.u[0] & 0xffffu) * c01.x, bf2f(q.u[0] >> 16) * c01.y);
        o.u[1] = pk2(bf2f(q.u[1] & 0xffffu) * c01.z, bf2f(q.u[1] >> 16) * c01.w);
        o.u[2] = pk2(bf2f(q.u[2] & 0xffffu) * c23.x, bf2f(q.u[2] >> 16) * c23.y);
        o.u[3] = pk2(bf2f(q.u[3] & 0xffffu) * c23.z, bf2f(q.u[3] >> 16) * c23.w);
        afr[mt] = o.v;
      }
      #pragma unroll
      for (int nt = 0; nt < 4; nt++) {
        int n = nt * 16 + l15;
        int byte = (n * 512 + kb * 2) ^ ((n & 7) << 4);
        bf16x8 bfr = *reinterpret_cast<bf16x8*>(reinterpret_cast<char*>(Qb) + byte);
        acc[0][nt] = __builtin_amdgcn_mfma_f32_16x16x32_bf16(afr[0], bfr, acc[0][nt], 0, 0, 0);
        acc[1][nt] = __builtin_amdgcn_mfma_f32_16x16x32_bf16(afr[1], bfr, acc[1][nt], 0, 0, 0);
      }
    }
    #pragma unroll
    for (int mt = 0; mt < 2; mt++)
      #pragma unroll
      for (int nt = 0; nt < 4; nt++)
        #pragma unroll
        for (int reg = 0; reg < 4; reg++) {
          int m = (half * 2 + mt) * 16 + g * 4 + reg;
          int n = nt * 16 + l15;
          S[k][m * 66 + n] = acc[mt][nt][reg];
        }
  }
  __syncthreads();

  // ---- masked exp + row sums ----
  for (int i = w; i < SQ; i += 8) {
    float p = 0.f;
    if (lane < SQ) {
      int sel = adjL[i * SQ + lane];
      if (sel > 0) p = __expf(S[sel - 1][i * 66 + lane]);
    }
    float s = p;
    #pragma unroll
    for (int off = 32; off; off >>= 1) s += __shfl_xor(s, off, 64);
    if (lane == 0) sinv[i] = (s > 0.f) ? 1.f / s : 0.f;
    int byte = (i * 128 + lane * 2) ^ ((i & 7) << 4);
    *reinterpret_cast<u16*>(reinterpret_cast<char*>(P) + byte) = f2bf(p);
  }
  __syncthreads();

  { // ---- PV: out[i][d] = sum_j P[i][j] hT[d][j] ----
    int mt = w >> 1, ng = w & 1;
    f32x4 acc[4];
    #pragma unroll
    for (int nt = 0; nt < 4; nt++) acc[nt] = (f32x4){0.f, 0.f, 0.f, 0.f};
    #pragma unroll
    for (int ks = 0; ks < 2; ks++) {
      int kb = ks * 32 + g * 8;
      int m = mt * 16 + l15;
      int abyte = (m * 128 + kb * 2) ^ ((m & 7) << 4);
      bf16x8 afr = *reinterpret_cast<bf16x8*>(reinterpret_cast<char*>(P) + abyte);
      #pragma unroll
      for (int nt = 0; nt < 4; nt++) {
        int d = (ng * 4 + nt) * 16 + l15;
        int byte = (d * 128 + kb * 2) ^ ((d & 7) << 4);
        bf16x8 bfr = *reinterpret_cast<bf16x8*>(reinterpret_cast<char*>(hTb) + byte);
        acc[nt] = __builtin_amdgcn_mfma_f32_16x16x32_bf16(afr, bfr, acc[nt], 0, 0, 0);
      }
    }
    float* dst = which ? tmpK : out_hidden;
    #pragma unroll
    for (int nt = 0; nt < 4; nt++)
      #pragma unroll
      for (int reg = 0; reg < 4; reg++) {
        int i = mt * 16 + g * 4 + reg;
        if (i < SQ) {
          int d = (ng * 4 + nt) * 16 + l15;
          dst[(size_t)(b * SQ + i) * DIM + d] = acc[nt][reg] * sinv[i];
        }
      }
  }
}

__global__ void add_kernel(float* __restrict__ out, const float* __restrict__ add) {
  int i = blockIdx.x * 256 + threadIdx.x;
  float4 a = reinterpret_cast<const float4*>(add)[i];
  float4 o = reinterpret_cast<float4*>(out)[i];
  o.x += a.x; o.y += a.y; o.z += a.z; o.w += a.w;
  reinterpret_cast<float4*>(out)[i] = o;
}

// ==================================================================
extern "C" void kernel_launch(void* const* d_in, const int* in_sizes, int n_in,
                              void* d_out, int out_size, void* d_ws, size_t ws_size,
                              hipStream_t stream) {
  const int*   inputs = (const int*)d_in[0];
  const int*   Aadj   = (const int*)d_in[1];
  const float* emb    = (const float*)d_in[3];
  const float* rembw  = (const float*)d_in[4];
  const float* transM = (const float*)d_in[5];
  const float* a0     = (const float*)d_in[6];
  const float* a1     = (const float*)d_in[7];
  const float* a2     = (const float*)d_in[8];
  const float* a3     = (const float*)d_in[9];
  const float* ain    = (const float*)d_in[10];
  const int*   hl     = (const int*)d_in[11];
  const int*   tl     = (const int*)d_in[12];

  // workspace layout (~52 MB)
  u32*   ego1b  = (u32*)d_ws;                       // N_NODE*64
  u32*   ego2b  = ego1b + (size_t)N_NODE * 64;      // N_NODE*64
  u32*   embb   = ego2b + (size_t)N_NODE * 64;      // N_NODE*64
  u16*   projb  = (u16*)(embb + (size_t)N_NODE * 64);   // N_NODE*128
  float* vperm  = (float*)(projb + (size_t)N_NODE * 128);
  int*   tperm  = (int*)(vperm + N_EDGES);
  int*   ipos   = tperm + N_EDGES;
  int*   cnt    = ipos + N_EDGES;
  int*   rowptr = cnt + N_NODE;
  int*   bsum   = rowptr + N_NODE + 64;
  float* tmpK   = (float*)(bsum + 256);

  float* out_hidden = (float*)d_out;
  float* out_node   = out_hidden + (size_t)BS * SQ * DIM;

  // ---- CSR build + emb conversion ----
  hipMemsetAsync(cnt, 0, N_NODE * sizeof(int), stream);
  conv_bf16<<<(N_NODE * 64) / 256, 256, 0, stream>>>(emb, embb);
  hist_kernel<<<N_EDGES / 256, 256, 0, stream>>>(hl, cnt);
  bsum_kernel<<<NB, 256, 0, stream>>>(cnt, bsum);
  scan_bsum_kernel<<<1, 256, 0, stream>>>(bsum);
  scan_final_kernel<<<NB, 256, 0, stream>>>(cnt, bsum, rowptr);
  scatter_kernel<<<N_EDGES / 256, 256, 0, stream>>>(hl, tl, ain, rowptr, cnt,
                                                    ipos, tperm, vperm);

  // ---- hop 0 ----
  spmm_csr_b<<<(N_NODE * 64) / 256, 256, 0, stream>>>(embb, vperm, tperm, rowptr, ego1b);

  // ---- update_attention ----
  for (int r = 0; r < N_REL; r++) {
    proj_mfma<<<(N_NODE + 127) / 128, 256, 0, stream>>>(
        ego1b, transM + (size_t)r * DIM * DIM, projb);
    edge_attn<<<PER_REL / 4, 256, 0, stream>>>(projb, hl, tl, rembw + r * DIM,
                                               ipos, vperm, r * PER_REL);
  }

  // ---- row softmax ----
  rowsoftmax<<<(N_NODE * 64) / 256, 256, 0, stream>>>(rowptr, vperm);

  // ---- hop 1 ----
  spmm_csr_b<<<(N_NODE * 64) / 256, 256, 0, stream>>>(ego1b, vperm, tperm, rowptr, ego2b);

  // ---- session-local double attention ----
  local_agg4<<<BS * 2, 512, 0, stream>>>(emb, ego1b, ego2b, inputs, Aadj,
                                         a0, a1, a2, a3, out_hidden, out_node, tmpK);
  add_kernel<<<(BS * SQ * DIM / 4) / 256, 256, 0, stream>>>(out_hidden, tmpK);
}

// Round 6
// 326.555 us; speedup vs baseline: 10.0603x; 1.4851x over previous
//
#include <hip/hip_runtime.h>

#define N_NODE  40000
#define DIM     128
#define N_REL   8
#define N_EDGES 640000
#define PER_REL (N_EDGES / N_REL)
#define BS      128
#define SQ      50
#define NB      ((N_NODE + 255) / 256)   // 157 scan blocks

typedef unsigned int        u32;
typedef unsigned short      u16;
typedef unsigned long long  u64;
typedef short  bf16x8 __attribute__((ext_vector_type(8)));
typedef float  f32x4  __attribute__((ext_vector_type(4)));

__device__ __forceinline__ u16 f2bf(float f) {
  union { float f; u32 i; } c; c.f = f;
  u32 b = c.i;
  b += 0x7FFFu + ((b >> 16) & 1u);   // RNE
  return (u16)(b >> 16);
}
__device__ __forceinline__ float bf2f(u32 u) {
  union { u32 i; float f; } c; c.i = u << 16; return c.f;
}
__device__ __forceinline__ u32 pk2(float a, float b) {
  return (u32)f2bf(a) | ((u32)f2bf(b) << 16);
}
__device__ __forceinline__ float tanh_fast(float x) {
  return 1.f - 2.f / (__expf(2.f * x) + 1.f);
}

// ==================================================================
// CSR build
// ==================================================================
__global__ void hist_kernel(const int* __restrict__ hl, int* __restrict__ cnt) {
  int e = blockIdx.x * 256 + threadIdx.x;
  if (e < N_EDGES) atomicAdd(&cnt[hl[e]], 1);
}

__global__ void bsum_kernel(const int* __restrict__ cnt, int* __restrict__ bsum) {
  __shared__ int sd[256];
  int i = blockIdx.x * 256 + threadIdx.x;
  sd[threadIdx.x] = (i < N_NODE) ? cnt[i] : 0;
  __syncthreads();
  for (int o = 128; o; o >>= 1) {
    if (threadIdx.x < o) sd[threadIdx.x] += sd[threadIdx.x + o];
    __syncthreads();
  }
  if (!threadIdx.x) bsum[blockIdx.x] = sd[0];
}

__global__ void scan_bsum_kernel(int* __restrict__ bsum) {
  __shared__ int sd[256];
  int t = threadIdx.x;
  int orig = (t < NB) ? bsum[t] : 0;
  sd[t] = orig;
  __syncthreads();
  for (int o = 1; o < 256; o <<= 1) {
    int v = (t >= o) ? sd[t - o] : 0;
    __syncthreads();
    sd[t] += v;
    __syncthreads();
  }
  if (t < NB) bsum[t] = sd[t] - orig;
}

__global__ void scan_final_kernel(const int* __restrict__ cnt, const int* __restrict__ bsum,
                                  int* __restrict__ rowptr) {
  __shared__ int sd[256];
  int t = threadIdx.x;
  int i = blockIdx.x * 256 + t;
  int orig = (i < N_NODE) ? cnt[i] : 0;
  sd[t] = orig;
  __syncthreads();
  for (int o = 1; o < 256; o <<= 1) {
    int v = (t >= o) ? sd[t - o] : 0;
    __syncthreads();
    sd[t] += v;
    __syncthreads();
  }
  int ex = sd[t] - orig + bsum[blockIdx.x];
  if (i < N_NODE) {
    rowptr[i] = ex;
    if (i == N_NODE - 1) rowptr[N_NODE] = ex + orig;
  }
}

// single 8B scatter per edge: pay = {t:16 | h:16 | r:4<<32 | bf16(ain)<<48}
__global__ void scatter_kernel(const int* __restrict__ hl, const int* __restrict__ tl,
                               const float* __restrict__ ain, const int* __restrict__ rowptr,
                               int* __restrict__ cnt, u64* __restrict__ pay) {
  int e = blockIdx.x * 256 + threadIdx.x;
  if (e >= N_EDGES) return;
  int hn = hl[e];
  int c = atomicSub(&cnt[hn], 1);
  int pos = rowptr[hn + 1] - c;
  int r = e / PER_REL;
  u32 lo = (u32)tl[e] | ((u32)hn << 16);
  u32 hi = (u32)r | ((u32)f2bf(ain[e]) << 16);
  pay[pos] = ((u64)hi << 32) | lo;
}

// ==================================================================
// f32 -> packed bf16 conversion (embedding)
// ==================================================================
__global__ void conv_bf16(const float* __restrict__ in, u32* __restrict__ out) {
  int i = blockIdx.x * 256 + threadIdx.x;
  float2 v = reinterpret_cast<const float2*>(in)[i];
  out[i] = pk2(v.x, v.y);
}

// ==================================================================
// hop0 spmm: weight = bf16 a_in from payload
// ==================================================================
__global__ void __launch_bounds__(256)
spmm_pay0(const u32* __restrict__ xb, const u64* __restrict__ pay,
          const int* __restrict__ rowptr, u32* __restrict__ outb) {
  int row = (blockIdx.x * 256 + threadIdx.x) >> 6;
  if (row >= N_NODE) return;
  int lane = threadIdx.x & 63;
  int lo = rowptr[row], n = rowptr[row + 1] - lo;
  float ax = 0.f, ay = 0.f;
  const u32* xl = xb + lane;
  int p = 0;
  for (; p + 1 < n; p += 2) {
    u64 q0 = pay[lo + p], q1 = pay[lo + p + 1];
    float v0 = bf2f((u32)(q0 >> 48)), v1 = bf2f((u32)(q1 >> 48));
    u32 w0 = xl[(size_t)(q0 & 0xffffu) << 6];
    u32 w1 = xl[(size_t)(q1 & 0xffffu) << 6];
    ax += v0 * bf2f(w0 & 0xffffu) + v1 * bf2f(w1 & 0xffffu);
    ay += v0 * bf2f(w0 >> 16)     + v1 * bf2f(w1 >> 16);
  }
  if (p < n) {
    u64 q0 = pay[lo + p];
    float v0 = bf2f((u32)(q0 >> 48));
    u32 w0 = xl[(size_t)(q0 & 0xffffu) << 6];
    ax += v0 * bf2f(w0 & 0xffffu);
    ay += v0 * bf2f(w0 >> 16);
  }
  outb[((size_t)row << 6) + lane] = pk2(ax, ay);
}

// ==================================================================
// hop1 spmm: weight = vals[p] (exp scores), scaled by 1/rowsum at end
// ==================================================================
__global__ void __launch_bounds__(256)
spmm_pay1(const u32* __restrict__ xb, const u64* __restrict__ pay,
          const float* __restrict__ vals, const int* __restrict__ rowptr,
          const float* __restrict__ rsum, u32* __restrict__ outb) {
  int row = (blockIdx.x * 256 + threadIdx.x) >> 6;
  if (row >= N_NODE) return;
  int lane = threadIdx.x & 63;
  int lo = rowptr[row], n = rowptr[row + 1] - lo;
  float ax = 0.f, ay = 0.f;
  const u32* xl = xb + lane;
  int p = 0;
  for (; p + 1 < n; p += 2) {
    u64 q0 = pay[lo + p], q1 = pay[lo + p + 1];
    float v0 = vals[lo + p], v1 = vals[lo + p + 1];
    u32 w0 = xl[(size_t)(q0 & 0xffffu) << 6];
    u32 w1 = xl[(size_t)(q1 & 0xffffu) << 6];
    ax += v0 * bf2f(w0 & 0xffffu) + v1 * bf2f(w1 & 0xffffu);
    ay += v0 * bf2f(w0 >> 16)     + v1 * bf2f(w1 >> 16);
  }
  if (p < n) {
    u64 q0 = pay[lo + p];
    float v0 = vals[lo + p];
    u32 w0 = xl[(size_t)(q0 & 0xffffu) << 6];
    ax += v0 * bf2f(w0 & 0xffffu);
    ay += v0 * bf2f(w0 >> 16);
  }
  float rs = rsum[row];
  float inv = (rs > 0.f) ? 1.f / rs : 0.f;
  outb[((size_t)row << 6) + lane] = pk2(ax * inv, ay * inv);
}

// ==================================================================
// all-relation projection: stage ego-tile once, loop 8 W matrices
// projb_all[r] = bf16( ego(bf16) @ W_r )
// ==================================================================
__global__ void __launch_bounds__(256)
proj_mfma_all(const u32* __restrict__ egob, const float* __restrict__ transM,
              u16* __restrict__ projb_all) {
  __shared__ u16 Al[128 * 128];   // [m][k] swizzled, 32 KB
  __shared__ u16 Bt[128 * 128];   // [n][k] swizzled, 32 KB
  int tid = threadIdx.x;
  int gbase = blockIdx.x * 128;

  for (int x = tid; x < 128 * 64; x += 256) {   // A: straight packed copy
    int m = x >> 6, d2 = x & 63;
    int gm = gbase + m; if (gm >= N_NODE) gm = N_NODE - 1;
    u32 v = egob[((size_t)gm << 6) + d2];
    int byte = (m * 256 + d2 * 4) ^ ((m & 7) << 4);
    *reinterpret_cast<u32*>(reinterpret_cast<char*>(Al) + byte) = v;
  }

  int w = tid >> 6, lane = tid & 63;
  int l15 = lane & 15, g = lane >> 4;

  for (int r = 0; r < N_REL; r++) {
    const float* Wg = transM + (size_t)r * DIM * DIM;
    for (int x = tid; x < 4096; x += 256) {     // W transposed -> [n][k]
      int k  = x >> 5;
      int nq = (x & 31) << 2;
      float4 v = *reinterpret_cast<const float4*>(Wg + k * DIM + nq);
      float fv[4] = {v.x, v.y, v.z, v.w};
      #pragma unroll
      for (int j = 0; j < 4; j++) {
        int n = nq + j;
        int byte = (n * 256 + k * 2) ^ ((n & 7) << 4);
        *reinterpret_cast<u16*>(reinterpret_cast<char*>(Bt) + byte) = f2bf(fv[j]);
      }
    }
    __syncthreads();

    f32x4 acc[2][8];
    #pragma unroll
    for (int mt = 0; mt < 2; mt++)
      #pragma unroll
      for (int nt = 0; nt < 8; nt++) acc[mt][nt] = (f32x4){0.f, 0.f, 0.f, 0.f};

    #pragma unroll
    for (int kk = 0; kk < 4; kk++) {
      int kb = (kk * 32 + g * 8) * 2;
      bf16x8 a[2];
      #pragma unroll
      for (int mt = 0; mt < 2; mt++) {
        int m = w * 32 + mt * 16 + l15;
        int byte = (m * 256 + kb) ^ ((m & 7) << 4);
        a[mt] = *reinterpret_cast<bf16x8*>(reinterpret_cast<char*>(Al) + byte);
      }
      #pragma unroll
      for (int nt = 0; nt < 8; nt++) {
        int n = nt * 16 + l15;
        int byte = (n * 256 + kb) ^ ((n & 7) << 4);
        bf16x8 b = *reinterpret_cast<bf16x8*>(reinterpret_cast<char*>(Bt) + byte);
        acc[0][nt] = __builtin_amdgcn_mfma_f32_16x16x32_bf16(a[0], b, acc[0][nt], 0, 0, 0);
        acc[1][nt] = __builtin_amdgcn_mfma_f32_16x16x32_bf16(a[1], b, acc[1][nt], 0, 0, 0);
      }
    }
    u16* projb = projb_all + (size_t)r * N_NODE * DIM;
    #pragma unroll
    for (int mt = 0; mt < 2; mt++) {
      #pragma unroll
      for (int reg = 0; reg < 4; reg++) {
        int node = gbase + w * 32 + mt * 16 + g * 4 + reg;
        if (node < N_NODE) {
          #pragma unroll
          for (int nt = 0; nt < 8; nt++)
            projb[(size_t)node * DIM + nt * 16 + l15] = f2bf(acc[mt][nt][reg]);
        }
      }
    }
    __syncthreads();   // Bt free for next r
  }
}

// ==================================================================
// per-relation constant: rsum8[r] = sum_d rembw[r][d]
// ==================================================================
__global__ void rsum8_kernel(const float* __restrict__ rembw, float* __restrict__ rsum8) {
  int r = threadIdx.x >> 6, lane = threadIdx.x & 63;
  float s = rembw[r * DIM + lane] + rembw[r * DIM + 64 + lane];
  #pragma unroll
  for (int o = 32; o; o >>= 1) s += __shfl_xor(s, o, 64);
  if (lane == 0) rsum8[r] = s;
}

// ==================================================================
// edge scoring in CSR order: 16 lanes/edge, 4 edges/wave, exp fused
// vals[p] = exp( sum_d tanh(proj_r[t]) * proj_r[h] + rsum8[r] )
// ==================================================================
__global__ void __launch_bounds__(256)
edge_attn_all(const u16* __restrict__ projb_all, const u64* __restrict__ pay,
              const float* __restrict__ rsum8, float* __restrict__ vals) {
  int tid = threadIdx.x;
  int p  = blockIdx.x * 16 + (tid >> 4);
  int le = tid & 15;
  u64 q = pay[p];
  int t = (int)(q & 0xffffu);
  int h = (int)((q >> 16) & 0xffffu);
  int r = (int)((q >> 32) & 0xfu);
  const u16* base = projb_all + (size_t)r * N_NODE * DIM;
  bf16x8 tv = *reinterpret_cast<const bf16x8*>(base + (size_t)t * DIM + le * 8);
  bf16x8 hv = *reinterpret_cast<const bf16x8*>(base + (size_t)h * DIM + le * 8);
  const u32* tw = reinterpret_cast<const u32*>(&tv);
  const u32* hw = reinterpret_cast<const u32*>(&hv);
  float s = 0.f;
  #pragma unroll
  for (int i = 0; i < 4; i++) {
    s += tanh_fast(bf2f(tw[i] & 0xffffu)) * bf2f(hw[i] & 0xffffu);
    s += tanh_fast(bf2f(tw[i] >> 16))     * bf2f(hw[i] >> 16);
  }
  #pragma unroll
  for (int o = 8; o; o >>= 1) s += __shfl_xor(s, o, 64);
  if (le == 0) vals[p] = __expf(s + rsum8[r]);
}

// ==================================================================
// per-row sum of exp scores (for hop1 normalization)
// ==================================================================
__global__ void __launch_bounds__(256)
rowsum_kernel(const int* __restrict__ rowptr, const float* __restrict__ vals,
              float* __restrict__ rsum) {
  int row = (blockIdx.x * 256 + threadIdx.x) >> 6;
  if (row >= N_NODE) return;
  int lane = threadIdx.x & 63;
  int lo = rowptr[row], n = rowptr[row + 1] - lo;
  float s = 0.f;
  for (int p = lane; p < n; p += 64) s += vals[lo + p];
  #pragma unroll
  for (int o = 32; o; o >>= 1) s += __shfl_xor(s, o, 64);
  if (lane == 0) rsum[row] = s;
}

// ==================================================================
// local_agg via MFMA (R5-proven)
// ==================================================================
__global__ void __launch_bounds__(512)
local_agg4(const float* __restrict__ emb, const u32* __restrict__ ego1b,
           const u32* __restrict__ ego2b, const int* __restrict__ inp,
           const int* __restrict__ Aadj,
           const float* __restrict__ a0, const float* __restrict__ a1,
           const float* __restrict__ a2, const float* __restrict__ a3,
           float* __restrict__ out_hidden, float* __restrict__ out_node,
           float* __restrict__ tmpK) {
  __shared__ u16   Qb[64 * 256];
  __shared__ u16   hTb[128 * 64];
  __shared__ float aC[4][256];
  __shared__ float S[4][64 * 66];
  __shared__ u16   P[64 * 64];
  __shared__ float sinv[64];
  __shared__ int   adjL[SQ * SQ];

  int b = blockIdx.x >> 1, which = blockIdx.x & 1;
  int tid = threadIdx.x;

  {
    int k = tid >> 7, d = tid & 127;
    const float* ap = (k == 0) ? a0 : (k == 1) ? a1 : (k == 2) ? a2 : a3;
    float av = ap[d];
    aC[k][d] = 0.6f * av;
    aC[k][128 + d] = 0.4f * av;
  }
  for (int x = tid; x < SQ * SQ; x += 512) adjL[x] = Aadj[b * SQ * SQ + x];
  for (int x = tid; x < 128 * 16; x += 512) {
    int d = x >> 4, j = 48 + (x & 15);
    if (j >= 50) {
      int byte = (d * 128 + j * 2) ^ ((d & 7) << 4);
      *reinterpret_cast<u16*>(reinterpret_cast<char*>(hTb) + byte) = 0;
    }
  }
  for (int x = tid; x < SQ * 64; x += 512) {
    int j = x >> 6, d2 = (x & 63) << 1;
    int node = inp[b * SQ + j];
    float v0, v1;
    if (which == 0) {
      float2 vv = *reinterpret_cast<const float2*>(emb + (size_t)node * DIM + d2);
      v0 = vv.x; v1 = vv.y;
      *reinterpret_cast<float2*>(out_node + (size_t)(b * SQ + j) * DIM + d2) = vv;
    } else {
      u32 w1 = ego1b[((size_t)node << 6) + (d2 >> 1)];
      u32 w2 = ego2b[((size_t)node << 6) + (d2 >> 1)];
      v0 = 0.5f * (bf2f(w1 & 0xffffu) + bf2f(w2 & 0xffffu));
      v1 = 0.5f * (bf2f(w1 >> 16) + bf2f(w2 >> 16));
    }
    u16 b0 = f2bf(v0), b1 = f2bf(v1);
    { int byte = (j * 512 + d2 * 2) ^ ((j & 7) << 4);
      *reinterpret_cast<u32*>(reinterpret_cast<char*>(Qb) + byte) = (u32)b0 | ((u32)b1 << 16); }
    { int byte = (j * 512 + 256 + d2 * 2) ^ ((j & 7) << 4);
      u32 m0 = b0 & 0x7fffu, m1 = b1 & 0x7fffu;
      *reinterpret_cast<u32*>(reinterpret_cast<char*>(Qb) + byte) = m0 | (m1 << 16); }
    { int byte = (d2 * 128 + j * 2) ^ ((d2 & 7) << 4);
      *reinterpret_cast<u16*>(reinterpret_cast<char*>(hTb) + byte) = b0; }
    { int byte = ((d2 + 1) * 128 + j * 2) ^ (((d2 + 1) & 7) << 4);
      *reinterpret_cast<u16*>(reinterpret_cast<char*>(hTb) + byte) = b1; }
  }
  __syncthreads();

  int w = tid >> 6, lane = tid & 63;
  int l15 = lane & 15, g = lane >> 4;

  {
    int k = w >> 1, half = w & 1;
    const float* aCk = aC[k];
    f32x4 acc[2][4];
    #pragma unroll
    for (int mt = 0; mt < 2; mt++)
      #pragma unroll
      for (int nt = 0; nt < 4; nt++) acc[mt][nt] = (f32x4){0.f, 0.f, 0.f, 0.f};
    for (int ks = 0; ks < 8; ks++) {
      int kb = ks * 32 + g * 8;
      float4 c01 = *reinterpret_cast<const float4*>(aCk + kb);
      float4 c23 = *reinterpret_cast<const float4*>(aCk + kb + 4);
      bf16x8 afr[2];
      #pragma unroll
      for (int mt = 0; mt < 2; mt++) {
        int m = (half * 2 + mt) * 16 + l15;
        int byte = (m * 512 + kb * 2) ^ ((m & 7) << 4);
        union { bf16x8 v; u32 u[4]; } qv, o;
        qv.v = *reinterpret_cast<bf16x8*>(reinterpret_cast<char*>(Qb) + byte);
        o.u[0] = pk2(bf2f(qv.u[0] & 0xffffu) * c01.x, bf2f(qv.u[0] >> 16) * c01.y);
        o.u[1] = pk2(bf2f(qv.u[1] & 0xffffu) * c01.z, bf2f(qv.u[1] >> 16) * c01.w);
        o.u[2] = pk2(bf2f(qv.u[2] & 0xffffu) * c23.x, bf2f(qv.u[2] >> 16) * c23.y);
        o.u[3] = pk2(bf2f(qv.u[3] & 0xffffu) * c23.z, bf2f(qv.u[3] >> 16) * c23.w);
        afr[mt] = o.v;
      }
      #pragma unroll
      for (int nt = 0; nt < 4; nt++) {
        int n = nt * 16 + l15;
        int byte = (n * 512 + kb * 2) ^ ((n & 7) << 4);
        bf16x8 bfr = *reinterpret_cast<bf16x8*>(reinterpret_cast<char*>(Qb) + byte);
        acc[0][nt] = __builtin_amdgcn_mfma_f32_16x16x32_bf16(afr[0], bfr, acc[0][nt], 0, 0, 0);
        acc[1][nt] = __builtin_amdgcn_mfma_f32_16x16x32_bf16(afr[1], bfr, acc[1][nt], 0, 0, 0);
      }
    }
    #pragma unroll
    for (int mt = 0; mt < 2; mt++)
      #pragma unroll
      for (int nt = 0; nt < 4; nt++)
        #pragma unroll
        for (int reg = 0; reg < 4; reg++) {
          int m = (half * 2 + mt) * 16 + g * 4 + reg;
          int n = nt * 16 + l15;
          S[k][m * 66 + n] = acc[mt][nt][reg];
        }
  }
  __syncthreads();

  for (int i = w; i < SQ; i += 8) {
    float p = 0.f;
    if (lane < SQ) {
      int sel = adjL[i * SQ + lane];
      if (sel > 0) p = __expf(S[sel - 1][i * 66 + lane]);
    }
    float s = p;
    #pragma unroll
    for (int off = 32; off; off >>= 1) s += __shfl_xor(s, off, 64);
    if (lane == 0) sinv[i] = (s > 0.f) ? 1.f / s : 0.f;
    int byte = (i * 128 + lane * 2) ^ ((i & 7) << 4);
    *reinterpret_cast<u16*>(reinterpret_cast<char*>(P) + byte) = f2bf(p);
  }
  __syncthreads();

  {
    int mt = w >> 1, ng = w & 1;
    f32x4 acc[4];
    #pragma unroll
    for (int nt = 0; nt < 4; nt++) acc[nt] = (f32x4){0.f, 0.f, 0.f, 0.f};
    #pragma unroll
    for (int ks = 0; ks < 2; ks++) {
      int kb = ks * 32 + g * 8;
      int m = mt * 16 + l15;
      int abyte = (m * 128 + kb * 2) ^ ((m & 7) << 4);
      bf16x8 afr = *reinterpret_cast<bf16x8*>(reinterpret_cast<char*>(P) + abyte);
      #pragma unroll
      for (int nt = 0; nt < 4; nt++) {
        int d = (ng * 4 + nt) * 16 + l15;
        int byte = (d * 128 + kb * 2) ^ ((d & 7) << 4);
        bf16x8 bfr = *reinterpret_cast<bf16x8*>(reinterpret_cast<char*>(hTb) + byte);
        acc[nt] = __builtin_amdgcn_mfma_f32_16x16x32_bf16(afr, bfr, acc[nt], 0, 0, 0);
      }
    }
    float* dst = which ? tmpK : out_hidden;
    #pragma unroll
    for (int nt = 0; nt < 4; nt++)
      #pragma unroll
      for (int reg = 0; reg < 4; reg++) {
        int i = mt * 16 + g * 4 + reg;
        if (i < SQ) {
          int d = (ng * 4 + nt) * 16 + l15;
          dst[(size_t)(b * SQ + i) * DIM + d] = acc[nt][reg] * sinv[i];
        }
      }
  }
}

__global__ void add_kernel(float* __restrict__ out, const float* __restrict__ add) {
  int i = blockIdx.x * 256 + threadIdx.x;
  float4 a = reinterpret_cast<const float4*>(add)[i];
  float4 o = reinterpret_cast<float4*>(out)[i];
  o.x += a.x; o.y += a.y; o.z += a.z; o.w += a.w;
  reinterpret_cast<float4*>(out)[i] = o;
}

// ==================================================================
extern "C" void kernel_launch(void* const* d_in, const int* in_sizes, int n_in,
                              void* d_out, int out_size, void* d_ws, size_t ws_size,
                              hipStream_t stream) {
  const int*   inputs = (const int*)d_in[0];
  const int*   Aadj   = (const int*)d_in[1];
  const float* emb    = (const float*)d_in[3];
  const float* rembw  = (const float*)d_in[4];
  const float* transM = (const float*)d_in[5];
  const float* a0     = (const float*)d_in[6];
  const float* a1     = (const float*)d_in[7];
  const float* a2     = (const float*)d_in[8];
  const float* a3     = (const float*)d_in[9];
  const float* ain    = (const float*)d_in[10];
  const int*   hl     = (const int*)d_in[11];
  const int*   tl     = (const int*)d_in[12];

  // workspace layout (~124 MB of the 256 MiB ws)
  u32*   ego1b    = (u32*)d_ws;                         // N_NODE*64 u32
  u32*   ego2b    = ego1b + (size_t)N_NODE * 64;
  u32*   embb     = ego2b + (size_t)N_NODE * 64;
  u16*   projball = (u16*)(embb + (size_t)N_NODE * 64); // 8*N_NODE*128 u16 = 82MB
  u64*   pay      = (u64*)(projball + (size_t)N_REL * N_NODE * DIM);
  float* vals     = (float*)(pay + N_EDGES);
  int*   cnt      = (int*)(vals + N_EDGES);
  int*   rowptr   = cnt + N_NODE;
  int*   bsum     = rowptr + N_NODE + 64;
  float* rsum     = (float*)(bsum + 256);
  float* rsum8    = rsum + N_NODE;
  float* tmpK     = rsum8 + 64;

  float* out_hidden = (float*)d_out;
  float* out_node   = out_hidden + (size_t)BS * SQ * DIM;

  // ---- CSR build + emb conversion ----
  hipMemsetAsync(cnt, 0, N_NODE * sizeof(int), stream);
  conv_bf16<<<(N_NODE * 64) / 256, 256, 0, stream>>>(emb, embb);
  hist_kernel<<<N_EDGES / 256, 256, 0, stream>>>(hl, cnt);
  bsum_kernel<<<NB, 256, 0, stream>>>(cnt, bsum);
  scan_bsum_kernel<<<1, 256, 0, stream>>>(bsum);
  scan_final_kernel<<<NB, 256, 0, stream>>>(cnt, bsum, rowptr);
  scatter_kernel<<<N_EDGES / 256, 256, 0, stream>>>(hl, tl, ain, rowptr, cnt, pay);

  // ---- hop 0 ----
  spmm_pay0<<<(N_NODE * 64) / 256, 256, 0, stream>>>(embb, pay, rowptr, ego1b);

  // ---- update_attention (batched) ----
  proj_mfma_all<<<(N_NODE + 127) / 128, 256, 0, stream>>>(ego1b, transM, projball);
  rsum8_kernel<<<1, 512, 0, stream>>>(rembw, rsum8);
  edge_attn_all<<<N_EDGES / 16, 256, 0, stream>>>(projball, pay, rsum8, vals);
  rowsum_kernel<<<(N_NODE * 64) / 256, 256, 0, stream>>>(rowptr, vals, rsum);

  // ---- hop 1 (softmax normalization fused via 1/rsum) ----
  spmm_pay1<<<(N_NODE * 64) / 256, 256, 0, stream>>>(ego1b, pay, vals, rowptr, rsum, ego2b);

  // ---- session-local double attention ----
  local_agg4<<<BS * 2, 512, 0, stream>>>(emb, ego1b, ego2b, inputs, Aadj,
                                         a0, a1, a2, a3, out_hidden, out_node, tmpK);
  add_kernel<<<(BS * SQ * DIM / 4) / 256, 256, 0, stream>>>(out_hidden, tmpK);
}

// Round 7
// 306.704 us; speedup vs baseline: 10.7115x; 1.0647x over previous
//
#include <hip/hip_runtime.h>

#define N_NODE  40000
#define DIM     128
#define N_REL   8
#define N_EDGES 640000
#define PER_REL (N_EDGES / N_REL)
#define BS      128
#define SQ      50
#define NB      ((N_NODE + 255) / 256)   // 157 scan blocks

typedef unsigned int        u32;
typedef unsigned short      u16;
typedef unsigned long long  u64;
typedef short  bf16x8 __attribute__((ext_vector_type(8)));
typedef float  f32x4  __attribute__((ext_vector_type(4)));

__device__ __forceinline__ u16 f2bf(float f) {
  union { float f; u32 i; } c; c.f = f;
  u32 b = c.i;
  b += 0x7FFFu + ((b >> 16) & 1u);   // RNE
  return (u16)(b >> 16);
}
__device__ __forceinline__ float bf2f(u32 u) {
  union { u32 i; float f; } c; c.i = u << 16; return c.f;
}
__device__ __forceinline__ u32 pk2(float a, float b) {
  return (u32)f2bf(a) | ((u32)f2bf(b) << 16);
}
__device__ __forceinline__ float tanh_fast(float x) {
  return 1.f - 2.f / (__expf(2.f * x) + 1.f);
}

// ==================================================================
// CSR build
// ==================================================================
__global__ void hist_kernel(const int* __restrict__ hl, int* __restrict__ cnt) {
  int e = blockIdx.x * 256 + threadIdx.x;
  if (e < N_EDGES) atomicAdd(&cnt[hl[e]], 1);
}

__global__ void bsum_kernel(const int* __restrict__ cnt, int* __restrict__ bsum) {
  __shared__ int sd[256];
  int i = blockIdx.x * 256 + threadIdx.x;
  sd[threadIdx.x] = (i < N_NODE) ? cnt[i] : 0;
  __syncthreads();
  for (int o = 128; o; o >>= 1) {
    if (threadIdx.x < o) sd[threadIdx.x] += sd[threadIdx.x + o];
    __syncthreads();
  }
  if (!threadIdx.x) bsum[blockIdx.x] = sd[0];
}

__global__ void scan_bsum_kernel(int* __restrict__ bsum) {
  __shared__ int sd[256];
  int t = threadIdx.x;
  int orig = (t < NB) ? bsum[t] : 0;
  sd[t] = orig;
  __syncthreads();
  for (int o = 1; o < 256; o <<= 1) {
    int v = (t >= o) ? sd[t - o] : 0;
    __syncthreads();
    sd[t] += v;
    __syncthreads();
  }
  if (t < NB) bsum[t] = sd[t] - orig;
}

__global__ void scan_final_kernel(const int* __restrict__ cnt, const int* __restrict__ bsum,
                                  int* __restrict__ rowptr) {
  __shared__ int sd[256];
  int t = threadIdx.x;
  int i = blockIdx.x * 256 + t;
  int orig = (i < N_NODE) ? cnt[i] : 0;
  sd[t] = orig;
  __syncthreads();
  for (int o = 1; o < 256; o <<= 1) {
    int v = (t >= o) ? sd[t - o] : 0;
    __syncthreads();
    sd[t] += v;
    __syncthreads();
  }
  int ex = sd[t] - orig + bsum[blockIdx.x];
  if (i < N_NODE) {
    rowptr[i] = ex;
    if (i == N_NODE - 1) rowptr[N_NODE] = ex + orig;
  }
}

// scatter: pay32[pos] = {t:16 | bf16(ain):16}; ipos[e] = pos (coalesced)
__global__ void scatter_kernel(const int* __restrict__ hl, const int* __restrict__ tl,
                               const float* __restrict__ ain, const int* __restrict__ rowptr,
                               int* __restrict__ cnt, u32* __restrict__ pay32,
                               int* __restrict__ ipos) {
  int e = blockIdx.x * 256 + threadIdx.x;
  if (e >= N_EDGES) return;
  int hn = hl[e];
  int c = atomicSub(&cnt[hn], 1);
  int pos = rowptr[hn + 1] - c;
  ipos[e] = pos;
  pay32[pos] = (u32)tl[e] | ((u32)f2bf(ain[e]) << 16);
}

// ==================================================================
// f32 -> packed bf16 conversion (embedding)
// ==================================================================
__global__ void conv_bf16(const float* __restrict__ in, u32* __restrict__ out) {
  int i = blockIdx.x * 256 + threadIdx.x;
  float2 v = reinterpret_cast<const float2*>(in)[i];
  out[i] = pk2(v.x, v.y);
}

// ==================================================================
// W transpose: Wtb[r][n][k] = bf16(W[r][k][n])   (one-shot, tiny)
// ==================================================================
__global__ void wtrans_kernel(const float* __restrict__ W, u16* __restrict__ Wtb) {
  int r = blockIdx.x;
  const float* Wr = W + (size_t)r * DIM * DIM;
  u16* o = Wtb + (size_t)r * DIM * DIM;
  for (int x = threadIdx.x; x < DIM * DIM; x += 256) {
    int n = x >> 7, k = x & 127;
    o[x] = f2bf(Wr[k * DIM + n]);
  }
}

// ==================================================================
// hop0 spmm: weight = bf16 a_in from pay32, unroll 4
// ==================================================================
__global__ void __launch_bounds__(256)
spmm_pay0(const u32* __restrict__ xb, const u32* __restrict__ pay32,
          const int* __restrict__ rowptr, u32* __restrict__ outb) {
  int row = (blockIdx.x * 256 + threadIdx.x) >> 6;
  if (row >= N_NODE) return;
  int lane = threadIdx.x & 63;
  int lo = rowptr[row], n = rowptr[row + 1] - lo;
  float ax = 0.f, ay = 0.f;
  const u32* xl = xb + lane;
  int p = 0;
  for (; p + 3 < n; p += 4) {
    u32 q0 = pay32[lo + p],     q1 = pay32[lo + p + 1];
    u32 q2 = pay32[lo + p + 2], q3 = pay32[lo + p + 3];
    u32 w0 = xl[(size_t)(q0 & 0xffffu) << 6];
    u32 w1 = xl[(size_t)(q1 & 0xffffu) << 6];
    u32 w2 = xl[(size_t)(q2 & 0xffffu) << 6];
    u32 w3 = xl[(size_t)(q3 & 0xffffu) << 6];
    float v0 = bf2f(q0 >> 16), v1 = bf2f(q1 >> 16);
    float v2 = bf2f(q2 >> 16), v3 = bf2f(q3 >> 16);
    ax += v0 * bf2f(w0 & 0xffffu) + v1 * bf2f(w1 & 0xffffu)
        + v2 * bf2f(w2 & 0xffffu) + v3 * bf2f(w3 & 0xffffu);
    ay += v0 * bf2f(w0 >> 16) + v1 * bf2f(w1 >> 16)
        + v2 * bf2f(w2 >> 16) + v3 * bf2f(w3 >> 16);
  }
  for (; p < n; p++) {
    u32 q0 = pay32[lo + p];
    float v0 = bf2f(q0 >> 16);
    u32 w0 = xl[(size_t)(q0 & 0xffffu) << 6];
    ax += v0 * bf2f(w0 & 0xffffu);
    ay += v0 * bf2f(w0 >> 16);
  }
  outb[((size_t)row << 6) + lane] = pk2(ax, ay);
}

// ==================================================================
// hop1 spmm: weight = vals[p] (exp scores), 1/rowsum at end, unroll 4
// ==================================================================
__global__ void __launch_bounds__(256)
spmm_pay1(const u32* __restrict__ xb, const u32* __restrict__ pay32,
          const float* __restrict__ vals, const int* __restrict__ rowptr,
          const float* __restrict__ rsum, u32* __restrict__ outb) {
  int row = (blockIdx.x * 256 + threadIdx.x) >> 6;
  if (row >= N_NODE) return;
  int lane = threadIdx.x & 63;
  int lo = rowptr[row], n = rowptr[row + 1] - lo;
  float ax = 0.f, ay = 0.f;
  const u32* xl = xb + lane;
  int p = 0;
  for (; p + 3 < n; p += 4) {
    u32 q0 = pay32[lo + p],     q1 = pay32[lo + p + 1];
    u32 q2 = pay32[lo + p + 2], q3 = pay32[lo + p + 3];
    float v0 = vals[lo + p],     v1 = vals[lo + p + 1];
    float v2 = vals[lo + p + 2], v3 = vals[lo + p + 3];
    u32 w0 = xl[(size_t)(q0 & 0xffffu) << 6];
    u32 w1 = xl[(size_t)(q1 & 0xffffu) << 6];
    u32 w2 = xl[(size_t)(q2 & 0xffffu) << 6];
    u32 w3 = xl[(size_t)(q3 & 0xffffu) << 6];
    ax += v0 * bf2f(w0 & 0xffffu) + v1 * bf2f(w1 & 0xffffu)
        + v2 * bf2f(w2 & 0xffffu) + v3 * bf2f(w3 & 0xffffu);
    ay += v0 * bf2f(w0 >> 16) + v1 * bf2f(w1 >> 16)
        + v2 * bf2f(w2 >> 16) + v3 * bf2f(w3 >> 16);
  }
  for (; p < n; p++) {
    u32 q0 = pay32[lo + p];
    float v0 = vals[lo + p];
    u32 w0 = xl[(size_t)(q0 & 0xffffu) << 6];
    ax += v0 * bf2f(w0 & 0xffffu);
    ay += v0 * bf2f(w0 >> 16);
  }
  float rs = rsum[row];
  float inv = (rs > 0.f) ? 1.f / rs : 0.f;
  outb[((size_t)row << 6) + lane] = pk2(ax * inv, ay * inv);
}

// ==================================================================
// all-relation projection v2: A in LDS (32 KB), B direct from global
// bf16 Wtb (32 KB per relation -> L1-resident inside the r-loop).
// ==================================================================
__global__ void __launch_bounds__(256)
proj_mfma2(const u32* __restrict__ egob, const u16* __restrict__ Wtb,
           u16* __restrict__ projb_all) {
  __shared__ u16 Al[128 * 128];   // [m][k] swizzled, 32 KB
  int tid = threadIdx.x;
  int gbase = blockIdx.x * 128;

  for (int x = tid; x < 128 * 64; x += 256) {   // A: straight packed copy
    int m = x >> 6, d2 = x & 63;
    int gm = gbase + m; if (gm >= N_NODE) gm = N_NODE - 1;
    u32 v = egob[((size_t)gm << 6) + d2];
    int byte = (m * 256 + d2 * 4) ^ ((m & 7) << 4);
    *reinterpret_cast<u32*>(reinterpret_cast<char*>(Al) + byte) = v;
  }
  __syncthreads();

  int w = tid >> 6, lane = tid & 63;
  int l15 = lane & 15, g = lane >> 4;

  // hoist A fragments: 8 regsets of bf16x8 (2 mt x 4 kk) = 32 VGPRs
  bf16x8 afr[2][4];
  #pragma unroll
  for (int kk = 0; kk < 4; kk++) {
    int kb = (kk * 32 + g * 8) * 2;
    #pragma unroll
    for (int mt = 0; mt < 2; mt++) {
      int m = w * 32 + mt * 16 + l15;
      int byte = (m * 256 + kb) ^ ((m & 7) << 4);
      afr[mt][kk] = *reinterpret_cast<bf16x8*>(reinterpret_cast<char*>(Al) + byte);
    }
  }

  for (int r = 0; r < N_REL; r++) {
    const u16* Wr = Wtb + (size_t)r * DIM * DIM;
    f32x4 acc[2][8];
    #pragma unroll
    for (int mt = 0; mt < 2; mt++)
      #pragma unroll
      for (int nt = 0; nt < 8; nt++) acc[mt][nt] = (f32x4){0.f, 0.f, 0.f, 0.f};

    #pragma unroll
    for (int kk = 0; kk < 4; kk++) {
      int ke = kk * 32 + g * 8;
      #pragma unroll
      for (int nt = 0; nt < 8; nt++) {
        int nidx = nt * 16 + l15;
        bf16x8 b = *reinterpret_cast<const bf16x8*>(Wr + nidx * DIM + ke);
        acc[0][nt] = __builtin_amdgcn_mfma_f32_16x16x32_bf16(afr[0][kk], b, acc[0][nt], 0, 0, 0);
        acc[1][nt] = __builtin_amdgcn_mfma_f32_16x16x32_bf16(afr[1][kk], b, acc[1][nt], 0, 0, 0);
      }
    }
    u16* projb = projb_all + (size_t)r * N_NODE * DIM;
    #pragma unroll
    for (int mt = 0; mt < 2; mt++) {
      #pragma unroll
      for (int reg = 0; reg < 4; reg++) {
        int node = gbase + w * 32 + mt * 16 + g * 4 + reg;
        if (node < N_NODE) {
          #pragma unroll
          for (int nt = 0; nt < 8; nt++)
            projb[(size_t)node * DIM + nt * 16 + l15] = f2bf(acc[mt][nt][reg]);
        }
      }
    }
  }
}

// ==================================================================
// per-relation constant: rsum8[r] = sum_d rembw[r][d]
// ==================================================================
__global__ void rsum8_kernel(const float* __restrict__ rembw, float* __restrict__ rsum8) {
  int r = threadIdx.x >> 6, lane = threadIdx.x & 63;
  float s = rembw[r * DIM + lane] + rembw[r * DIM + 64 + lane];
  #pragma unroll
  for (int o = 32; o; o >>= 1) s += __shfl_xor(s, o, 64);
  if (lane == 0) rsum8[r] = s;
}

// ==================================================================
// edge scoring in ORIGINAL relation-blocked order (L2-friendly gathers):
// vals[ipos[e]] = exp( sum_d tanh(proj_r[t]) * proj_r[h] + rsum8[r] )
// 16 lanes/edge, 4 edges/wave.
// ==================================================================
__global__ void __launch_bounds__(256)
edge_score(const u16* __restrict__ projb_all, const int* __restrict__ hl,
           const int* __restrict__ tl, const float* __restrict__ rsum8,
           const int* __restrict__ ipos, float* __restrict__ vals) {
  int tid = threadIdx.x;
  int e  = blockIdx.x * 16 + (tid >> 4);
  int le = tid & 15;
  int r = e / PER_REL;
  int t = tl[e], h = hl[e];
  const u16* base = projb_all + (size_t)r * N_NODE * DIM;
  bf16x8 tv = *reinterpret_cast<const bf16x8*>(base + (size_t)t * DIM + le * 8);
  bf16x8 hv = *reinterpret_cast<const bf16x8*>(base + (size_t)h * DIM + le * 8);
  const u32* tw = reinterpret_cast<const u32*>(&tv);
  const u32* hw = reinterpret_cast<const u32*>(&hv);
  float s = 0.f;
  #pragma unroll
  for (int i = 0; i < 4; i++) {
    s += tanh_fast(bf2f(tw[i] & 0xffffu)) * bf2f(hw[i] & 0xffffu);
    s += tanh_fast(bf2f(tw[i] >> 16))     * bf2f(hw[i] >> 16);
  }
  #pragma unroll
  for (int o = 8; o; o >>= 1) s += __shfl_xor(s, o, 64);
  if (le == 0) vals[ipos[e]] = __expf(s + rsum8[r]);
}

// ==================================================================
// per-row sum of exp scores (for hop1 normalization)
// ==================================================================
__global__ void __launch_bounds__(256)
rowsum_kernel(const int* __restrict__ rowptr, const float* __restrict__ vals,
              float* __restrict__ rsum) {
  int row = (blockIdx.x * 256 + threadIdx.x) >> 6;
  if (row >= N_NODE) return;
  int lane = threadIdx.x & 63;
  int lo = rowptr[row], n = rowptr[row + 1] - lo;
  float s = 0.f;
  for (int p = lane; p < n; p += 64) s += vals[lo + p];
  #pragma unroll
  for (int o = 32; o; o >>= 1) s += __shfl_xor(s, o, 64);
  if (lane == 0) rsum[row] = s;
}

// ==================================================================
// local_agg via MFMA (R5-proven, unchanged)
// ==================================================================
__global__ void __launch_bounds__(512)
local_agg4(const float* __restrict__ emb, const u32* __restrict__ ego1b,
           const u32* __restrict__ ego2b, const int* __restrict__ inp,
           const int* __restrict__ Aadj,
           const float* __restrict__ a0, const float* __restrict__ a1,
           const float* __restrict__ a2, const float* __restrict__ a3,
           float* __restrict__ out_hidden, float* __restrict__ out_node,
           float* __restrict__ tmpK) {
  __shared__ u16   Qb[64 * 256];
  __shared__ u16   hTb[128 * 64];
  __shared__ float aC[4][256];
  __shared__ float S[4][64 * 66];
  __shared__ u16   P[64 * 64];
  __shared__ float sinv[64];
  __shared__ int   adjL[SQ * SQ];

  int b = blockIdx.x >> 1, which = blockIdx.x & 1;
  int tid = threadIdx.x;

  {
    int k = tid >> 7, d = tid & 127;
    const float* ap = (k == 0) ? a0 : (k == 1) ? a1 : (k == 2) ? a2 : a3;
    float av = ap[d];
    aC[k][d] = 0.6f * av;
    aC[k][128 + d] = 0.4f * av;
  }
  for (int x = tid; x < SQ * SQ; x += 512) adjL[x] = Aadj[b * SQ * SQ + x];
  for (int x = tid; x < 128 * 16; x += 512) {
    int d = x >> 4, j = 48 + (x & 15);
    if (j >= 50) {
      int byte = (d * 128 + j * 2) ^ ((d & 7) << 4);
      *reinterpret_cast<u16*>(reinterpret_cast<char*>(hTb) + byte) = 0;
    }
  }
  for (int x = tid; x < SQ * 64; x += 512) {
    int j = x >> 6, d2 = (x & 63) << 1;
    int node = inp[b * SQ + j];
    float v0, v1;
    if (which == 0) {
      float2 vv = *reinterpret_cast<const float2*>(emb + (size_t)node * DIM + d2);
      v0 = vv.x; v1 = vv.y;
      *reinterpret_cast<float2*>(out_node + (size_t)(b * SQ + j) * DIM + d2) = vv;
    } else {
      u32 w1 = ego1b[((size_t)node << 6) + (d2 >> 1)];
      u32 w2 = ego2b[((size_t)node << 6) + (d2 >> 1)];
      v0 = 0.5f * (bf2f(w1 & 0xffffu) + bf2f(w2 & 0xffffu));
      v1 = 0.5f * (bf2f(w1 >> 16) + bf2f(w2 >> 16));
    }
    u16 b0 = f2bf(v0), b1 = f2bf(v1);
    { int byte = (j * 512 + d2 * 2) ^ ((j & 7) << 4);
      *reinterpret_cast<u32*>(reinterpret_cast<char*>(Qb) + byte) = (u32)b0 | ((u32)b1 << 16); }
    { int byte = (j * 512 + 256 + d2 * 2) ^ ((j & 7) << 4);
      u32 m0 = b0 & 0x7fffu, m1 = b1 & 0x7fffu;
      *reinterpret_cast<u32*>(reinterpret_cast<char*>(Qb) + byte) = m0 | (m1 << 16); }
    { int byte = (d2 * 128 + j * 2) ^ ((d2 & 7) << 4);
      *reinterpret_cast<u16*>(reinterpret_cast<char*>(hTb) + byte) = b0; }
    { int byte = ((d2 + 1) * 128 + j * 2) ^ (((d2 + 1) & 7) << 4);
      *reinterpret_cast<u16*>(reinterpret_cast<char*>(hTb) + byte) = b1; }
  }
  __syncthreads();

  int w = tid >> 6, lane = tid & 63;
  int l15 = lane & 15, g = lane >> 4;

  {
    int k = w >> 1, half = w & 1;
    const float* aCk = aC[k];
    f32x4 acc[2][4];
    #pragma unroll
    for (int mt = 0; mt < 2; mt++)
      #pragma unroll
      for (int nt = 0; nt < 4; nt++) acc[mt][nt] = (f32x4){0.f, 0.f, 0.f, 0.f};
    for (int ks = 0; ks < 8; ks++) {
      int kb = ks * 32 + g * 8;
      float4 c01 = *reinterpret_cast<const float4*>(aCk + kb);
      float4 c23 = *reinterpret_cast<const float4*>(aCk + kb + 4);
      bf16x8 afr[2];
      #pragma unroll
      for (int mt = 0; mt < 2; mt++) {
        int m = (half * 2 + mt) * 16 + l15;
        int byte = (m * 512 + kb * 2) ^ ((m & 7) << 4);
        union { bf16x8 v; u32 u[4]; } qv, o;
        qv.v = *reinterpret_cast<bf16x8*>(reinterpret_cast<char*>(Qb) + byte);
        o.u[0] = pk2(bf2f(qv.u[0] & 0xffffu) * c01.x, bf2f(qv.u[0] >> 16) * c01.y);
        o.u[1] = pk2(bf2f(qv.u[1] & 0xffffu) * c01.z, bf2f(qv.u[1] >> 16) * c01.w);
        o.u[2] = pk2(bf2f(qv.u[2] & 0xffffu) * c23.x, bf2f(qv.u[2] >> 16) * c23.y);
        o.u[3] = pk2(bf2f(qv.u[3] & 0xffffu) * c23.z, bf2f(qv.u[3] >> 16) * c23.w);
        afr[mt] = o.v;
      }
      #pragma unroll
      for (int nt = 0; nt < 4; nt++) {
        int n = nt * 16 + l15;
        int byte = (n * 512 + kb * 2) ^ ((n & 7) << 4);
        bf16x8 bfr = *reinterpret_cast<bf16x8*>(reinterpret_cast<char*>(Qb) + byte);
        acc[0][nt] = __builtin_amdgcn_mfma_f32_16x16x32_bf16(afr[0], bfr, acc[0][nt], 0, 0, 0);
        acc[1][nt] = __builtin_amdgcn_mfma_f32_16x16x32_bf16(afr[1], bfr, acc[1][nt], 0, 0, 0);
      }
    }
    #pragma unroll
    for (int mt = 0; mt < 2; mt++)
      #pragma unroll
      for (int nt = 0; nt < 4; nt++)
        #pragma unroll
        for (int reg = 0; reg < 4; reg++) {
          int m = (half * 2 + mt) * 16 + g * 4 + reg;
          int n = nt * 16 + l15;
          S[k][m * 66 + n] = acc[mt][nt][reg];
        }
  }
  __syncthreads();

  for (int i = w; i < SQ; i += 8) {
    float p = 0.f;
    if (lane < SQ) {
      int sel = adjL[i * SQ + lane];
      if (sel > 0) p = __expf(S[sel - 1][i * 66 + lane]);
    }
    float s = p;
    #pragma unroll
    for (int off = 32; off; off >>= 1) s += __shfl_xor(s, off, 64);
    if (lane == 0) sinv[i] = (s > 0.f) ? 1.f / s : 0.f;
    int byte = (i * 128 + lane * 2) ^ ((i & 7) << 4);
    *reinterpret_cast<u16*>(reinterpret_cast<char*>(P) + byte) = f2bf(p);
  }
  __syncthreads();

  {
    int mt = w >> 1, ng = w & 1;
    f32x4 acc[4];
    #pragma unroll
    for (int nt = 0; nt < 4; nt++) acc[nt] = (f32x4){0.f, 0.f, 0.f, 0.f};
    #pragma unroll
    for (int ks = 0; ks < 2; ks++) {
      int kb = ks * 32 + g * 8;
      int m = mt * 16 + l15;
      int abyte = (m * 128 + kb * 2) ^ ((m & 7) << 4);
      bf16x8 afr = *reinterpret_cast<bf16x8*>(reinterpret_cast<char*>(P) + abyte);
      #pragma unroll
      for (int nt = 0; nt < 4; nt++) {
        int d = (ng * 4 + nt) * 16 + l15;
        int byte = (d * 128 + kb * 2) ^ ((d & 7) << 4);
        bf16x8 bfr = *reinterpret_cast<bf16x8*>(reinterpret_cast<char*>(hTb) + byte);
        acc[nt] = __builtin_amdgcn_mfma_f32_16x16x32_bf16(afr, bfr, acc[nt], 0, 0, 0);
      }
    }
    float* dst = which ? tmpK : out_hidden;
    #pragma unroll
    for (int nt = 0; nt < 4; nt++)
      #pragma unroll
      for (int reg = 0; reg < 4; reg++) {
        int i = mt * 16 + g * 4 + reg;
        if (i < SQ) {
          int d = (ng * 4 + nt) * 16 + l15;
          dst[(size_t)(b * SQ + i) * DIM + d] = acc[nt][reg] * sinv[i];
        }
      }
  }
}

__global__ void add_kernel(float* __restrict__ out, const float* __restrict__ add) {
  int i = blockIdx.x * 256 + threadIdx.x;
  float4 a = reinterpret_cast<const float4*>(add)[i];
  float4 o = reinterpret_cast<float4*>(out)[i];
  o.x += a.x; o.y += a.y; o.z += a.z; o.w += a.w;
  reinterpret_cast<float4*>(out)[i] = o;
}

// ==================================================================
extern "C" void kernel_launch(void* const* d_in, const int* in_sizes, int n_in,
                              void* d_out, int out_size, void* d_ws, size_t ws_size,
                              hipStream_t stream) {
  const int*   inputs = (const int*)d_in[0];
  const int*   Aadj   = (const int*)d_in[1];
  const float* emb    = (const float*)d_in[3];
  const float* rembw  = (const float*)d_in[4];
  const float* transM = (const float*)d_in[5];
  const float* a0     = (const float*)d_in[6];
  const float* a1     = (const float*)d_in[7];
  const float* a2     = (const float*)d_in[8];
  const float* a3     = (const float*)d_in[9];
  const float* ain    = (const float*)d_in[10];
  const int*   hl     = (const int*)d_in[11];
  const int*   tl     = (const int*)d_in[12];

  // workspace layout (~116 MB of the 256 MiB ws)
  u32*   ego1b    = (u32*)d_ws;                         // N_NODE*64 u32
  u32*   ego2b    = ego1b + (size_t)N_NODE * 64;
  u32*   embb     = ego2b + (size_t)N_NODE * 64;
  u16*   projball = (u16*)(embb + (size_t)N_NODE * 64); // 8*N_NODE*128 u16 = 82MB
  u16*   Wtb      = projball + (size_t)N_REL * N_NODE * DIM;  // 128K u16
  u32*   pay32    = (u32*)(Wtb + (size_t)N_REL * DIM * DIM);
  int*   ipos     = (int*)(pay32 + N_EDGES);
  float* vals     = (float*)(ipos + N_EDGES);
  int*   cnt      = (int*)(vals + N_EDGES);
  int*   rowptr   = cnt + N_NODE;
  int*   bsum     = rowptr + N_NODE + 64;
  float* rsum     = (float*)(bsum + 256);
  float* rsum8    = rsum + N_NODE;
  float* tmpK     = rsum8 + 64;

  float* out_hidden = (float*)d_out;
  float* out_node   = out_hidden + (size_t)BS * SQ * DIM;

  // ---- CSR build + conversions ----
  hipMemsetAsync(cnt, 0, N_NODE * sizeof(int), stream);
  conv_bf16<<<(N_NODE * 64) / 256, 256, 0, stream>>>(emb, embb);
  wtrans_kernel<<<N_REL, 256, 0, stream>>>(transM, Wtb);
  rsum8_kernel<<<1, 512, 0, stream>>>(rembw, rsum8);
  hist_kernel<<<N_EDGES / 256, 256, 0, stream>>>(hl, cnt);
  bsum_kernel<<<NB, 256, 0, stream>>>(cnt, bsum);
  scan_bsum_kernel<<<1, 256, 0, stream>>>(bsum);
  scan_final_kernel<<<NB, 256, 0, stream>>>(cnt, bsum, rowptr);
  scatter_kernel<<<N_EDGES / 256, 256, 0, stream>>>(hl, tl, ain, rowptr, cnt, pay32, ipos);

  // ---- hop 0 ----
  spmm_pay0<<<(N_NODE * 64) / 256, 256, 0, stream>>>(embb, pay32, rowptr, ego1b);

  // ---- update_attention ----
  proj_mfma2<<<(N_NODE + 127) / 128, 256, 0, stream>>>(ego1b, Wtb, projball);
  edge_score<<<N_EDGES / 16, 256, 0, stream>>>(projball, hl, tl, rsum8, ipos, vals);
  rowsum_kernel<<<(N_NODE * 64) / 256, 256, 0, stream>>>(rowptr, vals, rsum);

  // ---- hop 1 (softmax normalization fused via 1/rsum) ----
  spmm_pay1<<<(N_NODE * 64) / 256, 256, 0, stream>>>(ego1b, pay32, vals, rowptr, rsum, ego2b);

  // ---- session-local double attention ----
  local_agg4<<<BS * 2, 512, 0, stream>>>(emb, ego1b, ego2b, inputs, Aadj,
                                         a0, a1, a2, a3, out_hidden, out_node, tmpK);
  add_kernel<<<(BS * SQ * DIM / 4) / 256, 256, 0, stream>>>(out_hidden, tmpK);
}